// Round 19
// baseline (724.645 us; speedup 1.0000x reference)
//
#include <hip/hip_runtime.h>

typedef unsigned short u16;
typedef unsigned int u32;
typedef unsigned long long u64;
typedef __attribute__((ext_vector_type(8))) short s16x8;
typedef __attribute__((ext_vector_type(4))) float f32x4;
typedef __attribute__((ext_vector_type(16))) float f32x16;

#define NTOK 4096
#define CAP 144

#define MFMA32(a,b,c) __builtin_amdgcn_mfma_f32_32x32x16_bf16(a,b,c,0,0,0)
#define MFMA16(a,b,c) __builtin_amdgcn_mfma_f32_16x16x32_bf16(a,b,c,0,0,0)

union U16x8 { uint4 u; u16 s[8]; };
union Dw4 { u32 d[4]; s16x8 v; };

__device__ __forceinline__ u16 f2bf(float f) {
    u32 u = __float_as_uint(f);
    u32 r = u + 0x7FFFu + ((u >> 16) & 1u);
    return (u16)(r >> 16);
}
__device__ __forceinline__ float bf2f(u16 v) { return __uint_as_float((u32)v << 16); }
__device__ __forceinline__ u32 pkbf(float lo, float hi) {
    u32 r;
    asm("v_cvt_pk_bf16_f32 %0, %1, %2" : "=v"(r) : "v"(lo), "v"(hi));
    return r;
}
__device__ __forceinline__ u32 mapkey(float f) {
    u32 b = __float_as_uint(f);
    return (b & 0x80000000u) ? ~b : (b | 0x80000000u);
}

// ---------------- row L2-normalize (128-wide rows) -> bf16 rows and/or f32 rows ----------------
__global__ __launch_bounds__(256) void norm_rows_kernel(const float* __restrict__ in,
                                                        u16* __restrict__ out16,
                                                        float* __restrict__ outRow, int rows)
{
    int row = blockIdx.x * 4 + (threadIdx.x >> 6);
    int lane = threadIdx.x & 63;
    if (row >= rows) return;
    float2 v = *(const float2*)&in[(size_t)row * 128 + lane * 2];
    float ss = v.x * v.x + v.y * v.y;
    #pragma unroll
    for (int o = 1; o < 64; o <<= 1) ss += __shfl_xor(ss, o);
    float rn = 1.0f / (sqrtf(ss) + 1e-8f);
    float2 ov = make_float2(v.x * rn, v.y * rn);
    if (out16)
        *(u32*)&out16[(size_t)row * 128 + lane * 2] = pkbf(ov.x, ov.y);
    if (outRow)
        *(float2*)&outRow[(size_t)row * 128 + lane * 2] = ov;
}

// ---------------- f32 -> bf16 cast ----------------
__global__ __launch_bounds__(256) void cast_bf16_kernel(const float* __restrict__ in,
                                                        u16* __restrict__ out, int n)
{
    int i = (blockIdx.x * 256 + threadIdx.x) * 4;
    if (i >= n) return;
    float4 v = *(const float4*)&in[i];
    ushort4 o;
    o.x = f2bf(v.x); o.y = f2bf(v.y); o.z = f2bf(v.z); o.w = f2bf(v.w);
    *(ushort4*)&out[i] = o;
}

// ---------------- gate-h bf16 rows ----------------
__global__ __launch_bounds__(256) void cast_gateh_kernel(const float* __restrict__ h, int stride,
                                                         int ngates, u16* __restrict__ out)
{
    int t = blockIdx.x, tid = threadIdx.x;
    int total = ngates * 128;
    for (int i = tid; i < total; i += 256) {
        int g = i >> 7, d = i & 127;
        out[(size_t)g * NTOK * 128 + (size_t)t * 128 + d] = f2bf(h[(size_t)t * stride + i]);
    }
}

// ---------------- transpose + cast: in f32 [Kk][Nn] -> out bf16 [Nn][Kk] ----------------
__global__ void transpose_cast_kernel(const float* __restrict__ in, u16* __restrict__ out,
                                      int Nn, int Kk)
{
    __shared__ float sT[64][65];
    int n0 = blockIdx.x * 64, k0 = blockIdx.y * 64;
    int tx = threadIdx.x, ty = threadIdx.y;
    #pragma unroll
    for (int r = 0; r < 64; r += 4)
        sT[ty + r][tx] = in[(size_t)(k0 + ty + r) * Nn + n0 + tx];
    __syncthreads();
    #pragma unroll
    for (int r = 0; r < 64; r += 4)
        out[(size_t)(n0 + ty + r) * Kk + k0 + tx] = f2bf(sT[tx][ty + r]);
}

// ---------------- per-cluster bf16 transpose: in [c][j][1024] -> out [c][d][NCLv] ----------------
__global__ void ntab_transpose_kernel(const u16* __restrict__ in, u16* __restrict__ out, int NCLv)
{
    __shared__ u16 tile[64][65];
    int cc = blockIdx.x, db = blockIdx.y * 64, jb = blockIdx.z * 64;
    int tx = threadIdx.x, ty = threadIdx.y;
    const u16* src = in + (size_t)cc * NCLv * 1024;
    #pragma unroll
    for (int r = 0; r < 64; r += 4)
        tile[ty + r][tx] = src[(size_t)(jb + ty + r) * 1024 + db + tx];
    __syncthreads();
    u16* dst = out + (size_t)cc * NCLv * 1024;
    #pragma unroll
    for (int r = 0; r < 64; r += 4)
        dst[(size_t)(db + ty + r) * NCLv + jb + tx] = tile[tx][ty + r];
}

// ---------------- LayerNorm (+fused bf16 copy) ----------------
__global__ __launch_bounds__(256) void ln_kernel(const float* __restrict__ x,
                                                 const float* __restrict__ gam,
                                                 const float* __restrict__ bet,
                                                 float* __restrict__ out,
                                                 u16* __restrict__ outbf)
{
    __shared__ float red[8];
    int t = blockIdx.x, tid = threadIdx.x;
    const float* row = x + (size_t)t * 1024;
    float4 v = *(const float4*)&row[tid * 4];
    float s = v.x + v.y + v.z + v.w;
    #pragma unroll
    for (int o = 1; o < 64; o <<= 1) s += __shfl_xor(s, o);
    if ((tid & 63) == 0) red[tid >> 6] = s;
    __syncthreads();
    float mean = (red[0] + red[1] + red[2] + red[3]) * (1.0f / 1024.0f);
    float d0 = v.x - mean, d1 = v.y - mean, d2 = v.z - mean, d3 = v.w - mean;
    float ss = d0 * d0 + d1 * d1 + d2 * d2 + d3 * d3;
    #pragma unroll
    for (int o = 1; o < 64; o <<= 1) ss += __shfl_xor(ss, o);
    if ((tid & 63) == 0) red[4 + (tid >> 6)] = ss;
    __syncthreads();
    float var = (red[4] + red[5] + red[6] + red[7]) * (1.0f / 1024.0f);
    float rstd = 1.0f / sqrtf(var + 1e-6f);
    int d = tid * 4;
    float4 g4 = *(const float4*)&gam[d];
    float4 b4 = *(const float4*)&bet[d];
    float4 o4;
    o4.x = d0 * rstd * g4.x + b4.x;
    o4.y = d1 * rstd * g4.y + b4.y;
    o4.z = d2 * rstd * g4.z + b4.z;
    o4.w = d3 * rstd * g4.w + b4.w;
    *(float4*)&out[(size_t)t * 1024 + d] = o4;
    if (outbf) {
        ushort4 ob;
        ob.x = f2bf(o4.x); ob.y = f2bf(o4.y); ob.z = f2bf(o4.z); ob.w = f2bf(o4.w);
        *(ushort4*)&outbf[(size_t)t * 1024 + d] = ob;
    }
}

// ---------------- bf16 MFMA GEMM ----------------
__global__ __launch_bounds__(256) void gemm_mfma_kernel(const u16* __restrict__ A,
                                                        const u16* __restrict__ Bt,
                                                        const float* __restrict__ bias,
                                                        const float* __restrict__ resid,
                                                        float* __restrict__ C, int N, int K)
{
    __shared__ __align__(16) u16 sA[128 * 80];
    __shared__ __align__(16) u16 sB[128 * 80];
    int n0 = blockIdx.x * 128, m0 = blockIdx.y * 128;
    int tid = threadIdx.x;
    int l = tid & 63, wid = tid >> 6;
    int wm = wid >> 1, wn = wid & 1;
    int l15 = l & 15, hi4 = l >> 4;
    f32x4 acc[4][4];
    #pragma unroll
    for (int i = 0; i < 4; ++i)
        #pragma unroll
        for (int j = 0; j < 4; ++j)
            #pragma unroll
            for (int q = 0; q < 4; ++q) acc[i][j][q] = 0.f;

    int sr = tid >> 1, scb = (tid & 1) * 4;
    for (int k0 = 0; k0 < K; k0 += 64) {
        __syncthreads();
        #pragma unroll
        for (int j = 0; j < 4; ++j) {
            int ch = scb + j;
            uint4 va = *(const uint4*)&A[(size_t)(m0 + sr) * K + k0 + ch * 8];
            *(uint4*)&sA[sr * 80 + ch * 8] = va;
            uint4 vb = *(const uint4*)&Bt[(size_t)(n0 + sr) * K + k0 + ch * 8];
            *(uint4*)&sB[sr * 80 + ch * 8] = vb;
        }
        __syncthreads();
        #pragma unroll
        for (int kc = 0; kc < 2; ++kc) {
            s16x8 af[4], bf[4];
            #pragma unroll
            for (int mf = 0; mf < 4; ++mf)
                af[mf] = *(const s16x8*)&sA[(wm * 64 + mf * 16 + l15) * 80 + kc * 32 + hi4 * 8];
            #pragma unroll
            for (int nf = 0; nf < 4; ++nf)
                bf[nf] = *(const s16x8*)&sB[(wn * 64 + nf * 16 + l15) * 80 + kc * 32 + hi4 * 8];
            #pragma unroll
            for (int mf = 0; mf < 4; ++mf)
                #pragma unroll
                for (int nf = 0; nf < 4; ++nf)
                    acc[mf][nf] = MFMA16(af[mf], bf[nf], acc[mf][nf]);
        }
    }
    #pragma unroll
    for (int mf = 0; mf < 4; ++mf)
        #pragma unroll
        for (int nf = 0; nf < 4; ++nf)
            #pragma unroll
            for (int j = 0; j < 4; ++j) {
                int row = m0 + wm * 64 + mf * 16 + hi4 * 4 + j;
                int col = n0 + wn * 64 + nf * 16 + l15;
                float v = acc[mf][nf][j];
                if (bias) v += bias[col];
                if (resid) v += resid[(size_t)row * N + col];
                C[(size_t)row * N + col] = v;
            }
}

// ---------------- tiny projection ----------------
__global__ __launch_bounds__(64) void vecproj_kernel(const float* __restrict__ h,
                                                     const float* __restrict__ W,
                                                     const float* __restrict__ bias,
                                                     float* __restrict__ out, int nw)
{
    int t = blockIdx.x, lane = threadIdx.x;
    float p0 = 0.f, p1 = 0.f, p2 = 0.f;
    #pragma unroll
    for (int it = 0; it < 4; ++it) {
        int d = it * 256 + lane * 4;
        float4 h4 = *(const float4*)&h[(size_t)t * 1024 + d];
        if (nw == 1) {
            float4 w4 = *(const float4*)&W[d];
            p0 += h4.x * w4.x + h4.y * w4.y + h4.z * w4.z + h4.w * w4.w;
        } else {
            float4 w0 = *(const float4*)&W[d * 3];
            float4 w1 = *(const float4*)&W[d * 3 + 4];
            float4 w2 = *(const float4*)&W[d * 3 + 8];
            p0 += h4.x * w0.x + h4.y * w0.w + h4.z * w1.z + h4.w * w2.y;
            p1 += h4.x * w0.y + h4.y * w1.x + h4.z * w1.w + h4.w * w2.z;
            p2 += h4.x * w0.z + h4.y * w1.y + h4.z * w2.x + h4.w * w2.w;
        }
    }
    #pragma unroll
    for (int o = 1; o < 64; o <<= 1) {
        p0 += __shfl_xor(p0, o);
        p1 += __shfl_xor(p1, o);
        p2 += __shfl_xor(p2, o);
    }
    if (lane == 0) {
        out[(size_t)t * nw + 0] = p0 + bias[0];
        if (nw > 1) out[(size_t)t * nw + 1] = p1 + bias[1];
        if (nw > 2) out[(size_t)t * nw + 2] = p2 + bias[2];
    }
}

// ---------------- cluster scores + softmax(cprob) + top-8, tiled f32 ----------------
__global__ __launch_bounds__(256) void cluster_kernel(
    const float* __restrict__ hsrc, int hstride,
    const float* __restrict__ cebase,
    float* __restrict__ cprob, int* __restrict__ topcg, int gate_base)
{
    __shared__ float sH[32 * 136];
    __shared__ float sC[64 * 136];
    int gy = blockIdx.y;
    const float* ce = cebase + (size_t)(gy >> 1) * (64 * 128);
    int hoff = gy * 128;
    int gout = gate_base + gy;
    int t0 = blockIdx.x * 32;
    int tid = threadIdx.x;

    {
        int r = tid >> 3, c0 = (tid & 7) * 16;
        const float* src = hsrc + (size_t)(t0 + r) * hstride + hoff + c0;
        #pragma unroll
        for (int q = 0; q < 16; q += 4)
            *(float4*)&sH[r * 136 + c0 + q] = *(const float4*)&src[q];
    }
    {
        int r = tid >> 2, c0 = (tid & 3) * 32;
        const float* src = ce + (size_t)r * 128 + c0;
        #pragma unroll
        for (int q = 0; q < 32; q += 4)
            *(float4*)&sC[r * 136 + c0 + q] = *(const float4*)&src[q];
    }
    __syncthreads();

    int tt = tid >> 3, cl0 = tid & 7;
    float acc[8] = {};
    for (int d4 = 0; d4 < 128; d4 += 4) {
        float4 hv = *(const float4*)&sH[tt * 136 + d4];
        #pragma unroll
        for (int c8 = 0; c8 < 8; ++c8) {
            float4 cv = *(const float4*)&sC[(cl0 + 8 * c8) * 136 + d4];
            acc[c8] = fmaf(hv.x, cv.x, acc[c8]);
            acc[c8] = fmaf(hv.y, cv.y, acc[c8]);
            acc[c8] = fmaf(hv.z, cv.z, acc[c8]);
            acc[c8] = fmaf(hv.w, cv.w, acc[c8]);
        }
    }
    __syncthreads();
    float* sS = sH;
    #pragma unroll
    for (int c8 = 0; c8 < 8; ++c8)
        sS[tt * 72 + cl0 + 8 * c8] = acc[c8];
    __syncthreads();

    int w = tid >> 6, lane = tid & 63;
    for (int k = 0; k < 8; ++k) {
        int t = w * 8 + k;
        float s = sS[t * 72 + lane];
        float mx = s;
        #pragma unroll
        for (int o = 1; o < 64; o <<= 1) mx = fmaxf(mx, __shfl_xor(mx, o));
        float e = expf(s - mx);
        float sm = e;
        #pragma unroll
        for (int o = 1; o < 64; o <<= 1) sm += __shfl_xor(sm, o);
        cprob[((size_t)gout * NTOK + t0 + t) * 64 + lane] = e / sm;
        int rank = 0;
        for (int j = 0; j < 64; ++j) {
            float sj = sS[t * 72 + j];
            rank += (sj > s || (sj == s && j < lane)) ? 1 : 0;
        }
        if (rank < 8) topcg[((size_t)gout * NTOK + t0 + t) * 8 + rank] = lane;
    }
}

// ---------------- build per-cluster padded (t,s) entry lists + 64-entry tile table ----------------
__global__ __launch_bounds__(1024) void listbuild_kernel(
    const int* __restrict__ topc_base, u32* __restrict__ entries_base,
    u32* __restrict__ tiletab_base, int* __restrict__ ntiles_base)
{
    __shared__ int cnt[64], offp[64], woff[64], tbase[64];
    int g = blockIdx.x;
    const int* tc = topc_base + (size_t)g * NTOK * 8;
    u32* eg = entries_base + (size_t)g * 40960;
    u32* tt = tiletab_base + (size_t)g * 640;
    int tid = threadIdx.x;
    if (tid < 64) { cnt[tid] = 0; woff[tid] = 0; }
    __syncthreads();
    int myc[32];
    #pragma unroll
    for (int i = 0; i < 32; ++i) {
        int t = tid * 4 + (i >> 3), s = i & 7;
        int c = tc[(size_t)t * 8 + s] & 63;
        myc[i] = c;
        atomicAdd(&cnt[c], 1);
    }
    __syncthreads();
    if (tid < 64) {
        int pc = (cnt[tid] + 63) & ~63;
        int sum = pc;
        #pragma unroll
        for (int o = 1; o < 64; o <<= 1) { int up = __shfl_up(sum, o); if (tid >= o) sum += up; }
        offp[tid] = sum - pc;
        int nt = pc >> 6;
        int tsum = nt;
        #pragma unroll
        for (int o = 1; o < 64; o <<= 1) { int up = __shfl_up(tsum, o); if (tid >= o) tsum += up; }
        tbase[tid] = tsum - nt;
        if (tid == 63) ntiles_base[g] = tsum;
    }
    __syncthreads();
    int totpad = offp[63] + ((cnt[63] + 63) & ~63);
    for (int i = tid; i < totpad; i += 1024) eg[i] = 0xFFFFFFFFu;
    __syncthreads();
    #pragma unroll
    for (int i = 0; i < 32; ++i) {
        int t = tid * 4 + (i >> 3), s = i & 7;
        int c = myc[i];
        int pos = offp[c] + atomicAdd(&woff[c], 1);
        eg[pos] = (u32)t | ((u32)s << 12);
    }
    __syncthreads();
    if (tid < 64) {
        int nt = ((cnt[tid] + 63) & ~63) >> 6;
        int eb = offp[tid] >> 6;
        for (int k2 = 0; k2 < nt; ++k2)
            tt[tbase[tid] + k2] = ((u32)tid << 16) | (u32)(eb + k2);
    }
}

// ---------------- block-sparse gate scoring (XCD-swizzled tiles) ----------------
template<int NCL>
__global__ __launch_bounds__(256) void score_bs_kernel(
    const u16* __restrict__ hgbf,
    const u16* __restrict__ embbase,
    float* __restrict__ scsbase,
    const u32* __restrict__ entries,
    const u32* __restrict__ tiletab,
    const int* __restrict__ ntiles)
{
    constexpr int NFR = NCL / 16;
    __shared__ __align__(16) u16 sH[64 * 136];
    __shared__ __align__(16) u16 sE[NCL * 136];
    __shared__ u32 ent[64];
    int gy = blockIdx.y;
    int bsw = ((int)blockIdx.x & 7) * 80 + ((int)blockIdx.x >> 3);
    if (bsw >= ntiles[gy]) return;
    u32 te = tiletab[(size_t)gy * 640 + bsw];
    int c = (int)(te >> 16) & 63;
    int e0 = (int)(te & 0x3FFu) * 64;
    const u32* eg = entries + (size_t)gy * 40960;
    const u16* Hg = hgbf + (size_t)gy * NTOK * 128;
    const u16* emb = embbase + (size_t)(gy >> 1) * 4096 * 128 + (size_t)c * NCL * 128;
    float* scs = scsbase + (size_t)gy * NTOK * (8 * NCL);

    int tid = threadIdx.x;
    int w = tid >> 6, lane = tid & 63;
    int l15 = lane & 15, hi4 = lane >> 4;

    if (tid < 64) ent[tid] = eg[e0 + tid];
    __syncthreads();

    #pragma unroll
    for (int u = 0; u < 4; ++u) {
        int idx = tid + u * 256;
        int r = idx >> 4, cq = idx & 15;
        int t = (int)(ent[r] & 4095u);
        uint4 v = *(const uint4*)&Hg[(size_t)t * 128 + cq * 8];
        *(uint4*)&sH[r * 136 + cq * 8] = v;
    }
    #pragma unroll
    for (int u = 0; u < NCL / 16; ++u) {
        int idx = tid + u * 256;
        int r = idx >> 4, cq = idx & 15;
        uint4 v = *(const uint4*)&emb[(size_t)r * 128 + cq * 8];
        *(uint4*)&sE[r * 136 + cq * 8] = v;
    }
    __syncthreads();

    f32x4 acc[NFR];
    #pragma unroll
    for (int nf = 0; nf < NFR; ++nf) { acc[nf][0] = 0.f; acc[nf][1] = 0.f; acc[nf][2] = 0.f; acc[nf][3] = 0.f; }
    #pragma unroll
    for (int kc = 0; kc < 4; ++kc) {
        s16x8 af = *(const s16x8*)&sH[(w * 16 + l15) * 136 + kc * 32 + hi4 * 8];
        #pragma unroll
        for (int nf = 0; nf < NFR; ++nf) {
            s16x8 bf = *(const s16x8*)&sE[(nf * 16 + l15) * 136 + kc * 32 + hi4 * 8];
            acc[nf] = MFMA16(af, bf, acc[nf]);
        }
    }

    int row0 = w * 16 + hi4 * 4;
    #pragma unroll
    for (int jj = 0; jj < 4; ++jj) {
        u32 e = ent[row0 + jj];
        if (e != 0xFFFFFFFFu) {
            int t = (int)(e & 4095u), s = (int)((e >> 12) & 7u);
            float* orow = scs + (size_t)t * (8 * NCL) + s * NCL;
            #pragma unroll
            for (int nf = 0; nf < NFR; ++nf)
                orow[nf * 16 + l15] = acc[nf][jj];
        }
    }
}

// ---------------- gate select over precomputed dense scores ----------------
template<int NCAND, int LGCS>
__global__ __launch_bounds__(256) void gate_select_kernel(
    float* __restrict__ scsg,
    const float* __restrict__ tausrc, int taustride,
    const int* __restrict__ topcg,
    int* __restrict__ gidx, float* __restrict__ gval, int* __restrict__ gcnt,
    int gate_base)
{
    constexpr int CSM = (1 << LGCS) - 1;
    __shared__ float lds_scs[4][NCAND];
    __shared__ int   lds_hist[4][256];
    __shared__ int   lds_topc[4][8];
    __shared__ float lds_keg[4][CAP];

    int gy = blockIdx.y;
    int gg = gate_base + gy;
    int tauoff = gy;
    const int* tsrc = topcg + (size_t)gg * NTOK * 8;
    float* scs = scsg + (size_t)gy * NTOK * NCAND;
    gidx += (size_t)gg * NTOK * CAP;
    gval += (size_t)gg * NTOK * CAP;
    gcnt += gg * NTOK;

    int w = threadIdx.x >> 6, lane = threadIdx.x & 63;
    int t = blockIdx.x * 4 + w;

    float* srow = scs + (size_t)t * NCAND;
    #pragma unroll
    for (int c0 = 0; c0 < NCAND; c0 += 64)
        lds_scs[w][c0 + lane] = srow[c0 + lane];
    if (lane < 8) lds_topc[w][lane] = tsrc[(size_t)t * 8 + lane] & 63;

    unsigned prefix = 0; int k = 128;
    #pragma unroll
    for (int shift = 24; shift >= 0; shift -= 8) {
        lds_hist[w][lane] = 0;
        lds_hist[w][lane + 64] = 0;
        lds_hist[w][lane + 128] = 0;
        lds_hist[w][lane + 192] = 0;
        unsigned mhi = (shift == 24) ? 0u : (0xFFFFFFFFu << (shift + 8));
        #pragma unroll
        for (int ii = 0; ii < NCAND; ii += 64) {
            unsigned key = mapkey(lds_scs[w][ii + lane]);
            if ((key & mhi) == prefix) atomicAdd(&lds_hist[w][(key >> shift) & 255], 1);
        }
        int s0 = lds_hist[w][4 * lane], s1 = lds_hist[w][4 * lane + 1];
        int s2 = lds_hist[w][4 * lane + 2], s3 = lds_hist[w][4 * lane + 3];
        int sl = s0 + s1 + s2 + s3;
        int suf = sl;
        #pragma unroll
        for (int o = 1; o < 64; o <<= 1) {
            int ov = __shfl_down(suf, o);
            if (lane + o < 64) suf += ov;
        }
        int run = suf - sl;
        int seld = -1, selk = 0;
        if (run < k && k <= run + s3) { seld = 4 * lane + 3; selk = k - run; }
        run += s3;
        if (seld < 0 && run < k && k <= run + s2) { seld = 4 * lane + 2; selk = k - run; }
        run += s2;
        if (seld < 0 && run < k && k <= run + s1) { seld = 4 * lane + 1; selk = k - run; }
        run += s1;
        if (seld < 0 && run < k && k <= run + s0) { seld = 4 * lane + 0; selk = k - run; }
        u64 mk = __ballot(seld >= 0);
        int owner = __ffsll(mk) - 1;
        int sd = __shfl(seld, owner);
        k = __shfl(selk, owner);
        prefix |= ((unsigned)sd) << shift;
    }
    unsigned thrkey = prefix;

    float tau = tausrc[(size_t)t * taustride + tauoff];
    int basec = 0;
    float lsum = 0.f, lmaxs = -3.0e38f;
    #pragma unroll
    for (int c0 = 0; c0 < NCAND; c0 += 64) {
        float s = lds_scs[w][c0 + lane];
        lmaxs = fmaxf(lmaxs, s);
        bool pred = (mapkey(s) >= thrkey);
        float eg = 0.f;
        if (pred) {
            float raw = s - tau;
            float g2 = raw > 0.f ? raw : 1e-8f * expf(raw);
            eg = expf(g2) - 1.0f;
            lsum += eg;
        }
        u64 mk = __ballot(pred);
        int pos = basec + __popcll(mk & ((1ull << lane) - 1ull));
        if (pred && pos < CAP) {
            lds_hist[w][pos] = c0 + lane;
            lds_keg[w][pos] = eg;
        }
        basec += __popcll(mk);
    }
    #pragma unroll
    for (int o = 1; o < 64; o <<= 1) {
        lsum += __shfl_xor(lsum, o);
        lmaxs = fmaxf(lmaxs, __shfl_xor(lmaxs, o));
    }
    float rawm = lmaxs - tau;
    float gm = rawm > 0.f ? rawm : 1e-8f * expf(rawm);
    float egm = expf(gm) - 1.0f;
    float scalev = tanhf(egm) / (lsum + 1e-8f);
    int nkept = basec < CAP ? basec : CAP;

    for (int p = lane; p < nkept; p += 64) {
        int i = lds_hist[w][p];
        float eg = lds_keg[w][p];
        int neuron = (lds_topc[w][i >> LGCS] << LGCS) + (i & CSM);
        gidx[(size_t)t * CAP + p] = neuron;
        gval[(size_t)t * CAP + p] = eg * scalev;
    }
    if (lane == 0) gcnt[t] = nkept;

    #pragma unroll
    for (int c0 = 0; c0 < NCAND; c0 += 64) {
        int i = c0 + lane;
        float s = lds_scs[w][i];
        float wv = 0.f;
        if (mapkey(s) >= thrkey) {
            float raw = s - tau;
            float g2 = raw > 0.f ? raw : 1e-8f * expf(raw);
            wv = (expf(g2) - 1.0f) * scalev;
        }
        srow[i] = wv;
    }
}

// ---------------- fused attn sense+emit over 3 gates (NCL=64, padded sP) ----------------
__global__ __launch_bounds__(256) void sense_bs_attn_kernel(
    const u16* __restrict__ hbf,
    const u16* __restrict__ ntab_qk, const u16* __restrict__ ntabT_qk,
    const u16* __restrict__ ntab_v,  const u16* __restrict__ ntabT_v,
    const float* __restrict__ Wbase,
    const u32* __restrict__ entries_base,
    const u32* __restrict__ tiletab_base,
    const int* __restrict__ ntiles_base,
    u16* __restrict__ partial_base, size_t pstride, int gate_base)
{
    constexpr int NCL = 64;
    constexpr int NTP = 72;
    constexpr int PS  = 72;
    constexpr int NFR = 4;
    constexpr int LQ  = 3;
    __shared__ __align__(16) char smem[(64 + NCL) * 144 + 64 * PS * 2 + 256];
    u16* sH = (u16*)smem;
    u16* sN = (u16*)(smem + 64 * 144);
    u16* sNT = (u16*)smem;
    u16* sP = (u16*)(smem + (64 + NCL) * 144);
    u32* ent = (u32*)(smem + (64 + NCL) * 144 + 64 * PS * 2);

    int gy = gate_base + (int)blockIdx.y;
    int bsw = ((int)blockIdx.x & 7) * 80 + ((int)blockIdx.x >> 3);
    if (bsw >= ntiles_base[gy]) return;
    u32 te = tiletab_base[(size_t)gy * 640 + bsw];
    int c = (int)(te >> 16) & 63;
    int e0 = (int)(te & 0x3FFu) * 64;

    const u32* entries = entries_base + (size_t)gy * 40960;
    const float* Wg = Wbase + (size_t)gy * NTOK * 512;
    const u16* ntab  = (gy == 2) ? ntab_v  : ntab_qk;
    const u16* ntabT = (gy == 2) ? ntabT_v : ntabT_qk;
    u16* partial = partial_base + (size_t)blockIdx.y * pstride;

    int tid = threadIdx.x;
    int w = tid >> 6, lane = tid & 63;
    int l15 = lane & 15, hi4 = lane >> 4;

    if (tid < 64) ent[tid] = entries[e0 + tid];
    __syncthreads();

    const u16* nbase = ntab + (size_t)c * NCL * 1024;
    const u16* ntT = ntabT + (size_t)c * NCL * 1024;

    f32x4 acc[NFR];
    #pragma unroll
    for (int nf = 0; nf < NFR; ++nf) { acc[nf][0] = 0.f; acc[nf][1] = 0.f; acc[nf][2] = 0.f; acc[nf][3] = 0.f; }

    for (int k0 = 0; k0 < 1024; k0 += 64) {
        __syncthreads();
        #pragma unroll
        for (int u = 0; u < 2; ++u) {
            int idx = tid + u * 256;
            int r = idx >> 3, cq = idx & 7;
            int t = (int)(ent[r] & 4095u);
            uint4 v = *(const uint4*)&hbf[(size_t)t * 1024 + k0 + cq * 8];
            *(uint4*)&sH[r * 72 + cq * 8] = v;
        }
        #pragma unroll
        for (int u = 0; u < 2; ++u) {
            int idx = tid + u * 256;
            int r = idx >> 3, cq = idx & 7;
            uint4 v = *(const uint4*)&nbase[(size_t)r * 1024 + k0 + cq * 8];
            *(uint4*)&sN[r * 72 + cq * 8] = v;
        }
        __syncthreads();
        #pragma unroll
        for (int kc = 0; kc < 2; ++kc) {
            s16x8 af = *(const s16x8*)&sH[(w * 16 + l15) * 72 + kc * 32 + hi4 * 8];
            #pragma unroll
            for (int nf = 0; nf < NFR; ++nf) {
                s16x8 bf = *(const s16x8*)&sN[(nf * 16 + l15) * 72 + kc * 32 + hi4 * 8];
                acc[nf] = MFMA16(af, bf, acc[nf]);
            }
        }
    }
    __syncthreads();

    int row0 = w * 16 + hi4 * 4;
    u32 erow[4]; bool evalid[4];
    #pragma unroll
    for (int jj = 0; jj < 4; ++jj) { erow[jj] = ent[row0 + jj]; evalid[jj] = (erow[jj] != 0xFFFFFFFFu); }
    #pragma unroll
    for (int jj = 0; jj < 4; ++jj) {
        int t = (int)(erow[jj] & 4095u), s = (int)((erow[jj] >> 12) & 7u);
        const float* wrow = Wg + (size_t)t * (8 * NCL) + s * NCL;
        #pragma unroll
        for (int nf = 0; nf < NFR; ++nf) {
            float wv = wrow[nf * 16 + l15];
            sP[(row0 + jj) * PS + nf * 16 + l15] = f2bf(acc[nf][jj] * wv);
        }
    }
    __syncthreads();

    for (int dch = 0; dch < 16; ++dch) {
        int d0 = dch * 64;
        __syncthreads();
        #pragma unroll
        for (int u = 0; u < 2; ++u) {
            int v = tid + u * 256;
            int dr = v >> LQ, jq = v & ((1 << LQ) - 1);
            uint4 t4 = *(const uint4*)&ntT[(size_t)(d0 + dr) * NCL + jq * 8];
            *(uint4*)&sNT[dr * NTP + jq * 8] = t4;
        }
        __syncthreads();
        f32x4 ab[4];
        #pragma unroll
        for (int df = 0; df < 4; ++df) { ab[df][0] = 0.f; ab[df][1] = 0.f; ab[df][2] = 0.f; ab[df][3] = 0.f; }
        #pragma unroll
        for (int kc = 0; kc < 2; ++kc) {
            s16x8 af = *(const s16x8*)&sP[(w * 16 + l15) * PS + kc * 32 + hi4 * 8];
            #pragma unroll
            for (int df = 0; df < 4; ++df) {
                s16x8 bf = *(const s16x8*)&sNT[(df * 16 + l15) * NTP + kc * 32 + hi4 * 8];
                ab[df] = MFMA16(af, bf, ab[df]);
            }
        }
        #pragma unroll
        for (int jj = 0; jj < 4; ++jj) {
            if (evalid[jj]) {
                int t = (int)(erow[jj] & 4095u), s = (int)((erow[jj] >> 12) & 7u);
                u16* prow = partial + ((size_t)t * 8 + s) * 1024 + d0;
                #pragma unroll
                for (int df = 0; df < 4; ++df)
                    prow[df * 16 + l15] = f2bf(ab[df][jj]);
            }
        }
    }
}

// ---------------- block-sparse sense+emit, know gate (padded sP) ----------------
template<int NCL>
__global__ __launch_bounds__(256) void sense_bs_kernel(
    const u16* __restrict__ hbf,
    const u16* __restrict__ ntab,
    const u16* __restrict__ ntabT,
    const float* __restrict__ Wg,
    const u32* __restrict__ entries,
    const u32* __restrict__ tiletab,
    const int* __restrict__ ntiles,
    u16* __restrict__ partial)
{
    constexpr int NTP = NCL + 8;
    constexpr int PS  = NCL + 8;
    constexpr int NFR = NCL / 16;
    constexpr int LQ = (NCL == 64) ? 3 : 4;
    __shared__ __align__(16) char smem[(64 + NCL) * 144 + 64 * PS * 2 + 256];
    u16* sH = (u16*)smem;
    u16* sN = (u16*)(smem + 64 * 144);
    u16* sNT = (u16*)smem;
    u16* sP = (u16*)(smem + (64 + NCL) * 144);
    u32* ent = (u32*)(smem + (64 + NCL) * 144 + 64 * PS * 2);

    int bsw = ((int)blockIdx.x & 7) * 80 + ((int)blockIdx.x >> 3);
    if (bsw >= *ntiles) return;
    u32 te = tiletab[bsw];
    int c = (int)(te >> 16) & 63;
    int e0 = (int)(te & 0x3FFu) * 64;

    int tid = threadIdx.x;
    int w = tid >> 6, lane = tid & 63;
    int l15 = lane & 15, hi4 = lane >> 4;

    if (tid < 64) ent[tid] = entries[e0 + tid];
    __syncthreads();

    const u16* nbase = ntab + (size_t)c * NCL * 1024;
    const u16* ntT = ntabT + (size_t)c * NCL * 1024;

    f32x4 acc[NFR];
    #pragma unroll
    for (int nf = 0; nf < NFR; ++nf) { acc[nf][0] = 0.f; acc[nf][1] = 0.f; acc[nf][2] = 0.f; acc[nf][3] = 0.f; }

    for (int k0 = 0; k0 < 1024; k0 += 64) {
        __syncthreads();
        #pragma unroll
        for (int u = 0; u < 2; ++u) {
            int idx = tid + u * 256;
            int r = idx >> 3, cq = idx & 7;
            int t = (int)(ent[r] & 4095u);
            uint4 v = *(const uint4*)&hbf[(size_t)t * 1024 + k0 + cq * 8];
            *(uint4*)&sH[r * 72 + cq * 8] = v;
        }
        #pragma unroll
        for (int u = 0; u < NCL / 32; ++u) {
            int idx = tid + u * 256;
            int r = idx >> 3, cq = idx & 7;
            uint4 v = *(const uint4*)&nbase[(size_t)r * 1024 + k0 + cq * 8];
            *(uint4*)&sN[r * 72 + cq * 8] = v;
        }
        __syncthreads();
        #pragma unroll
        for (int kc = 0; kc < 2; ++kc) {
            s16x8 af = *(const s16x8*)&sH[(w * 16 + l15) * 72 + kc * 32 + hi4 * 8];
            #pragma unroll
            for (int nf = 0; nf < NFR; ++nf) {
                s16x8 bf = *(const s16x8*)&sN[(nf * 16 + l15) * 72 + kc * 32 + hi4 * 8];
                acc[nf] = MFMA16(af, bf, acc[nf]);
            }
        }
    }
    __syncthreads();

    int row0 = w * 16 + hi4 * 4;
    u32 erow[4]; bool evalid[4];
    #pragma unroll
    for (int jj = 0; jj < 4; ++jj) { erow[jj] = ent[row0 + jj]; evalid[jj] = (erow[jj] != 0xFFFFFFFFu); }
    #pragma unroll
    for (int jj = 0; jj < 4; ++jj) {
        int t = (int)(erow[jj] & 4095u), s = (int)((erow[jj] >> 12) & 7u);
        const float* wrow = Wg + (size_t)t * (8 * NCL) + s * NCL;
        #pragma unroll
        for (int nf = 0; nf < NFR; ++nf) {
            float wv = wrow[nf * 16 + l15];
            sP[(row0 + jj) * PS + nf * 16 + l15] = f2bf(acc[nf][jj] * wv);
        }
    }
    __syncthreads();

    for (int dch = 0; dch < 16; ++dch) {
        int d0 = dch * 64;
        __syncthreads();
        #pragma unroll
        for (int u = 0; u < NCL / 32; ++u) {
            int v = tid + u * 256;
            int dr = v >> LQ, jq = v & ((1 << LQ) - 1);
            uint4 t4 = *(const uint4*)&ntT[(size_t)(d0 + dr) * NCL + jq * 8];
            *(uint4*)&sNT[dr * NTP + jq * 8] = t4;
        }
        __syncthreads();
        f32x4 ab[4];
        #pragma unroll
        for (int df = 0; df < 4; ++df) { ab[df][0] = 0.f; ab[df][1] = 0.f; ab[df][2] = 0.f; ab[df][3] = 0.f; }
        #pragma unroll
        for (int kc = 0; kc < NCL / 32; ++kc) {
            s16x8 af = *(const s16x8*)&sP[(w * 16 + l15) * PS + kc * 32 + hi4 * 8];
            #pragma unroll
            for (int df = 0; df < 4; ++df) {
                s16x8 bf = *(const s16x8*)&sNT[(df * 16 + l15) * NTP + kc * 32 + hi4 * 8];
                ab[df] = MFMA16(af, bf, ab[df]);
            }
        }
        #pragma unroll
        for (int jj = 0; jj < 4; ++jj) {
            if (evalid[jj]) {
                int t = (int)(erow[jj] & 4095u), s = (int)((erow[jj] >> 12) & 7u);
                u16* prow = partial + ((size_t)t * 8 + s) * 1024 + d0;
                #pragma unroll
                for (int df = 0; df < 4; ++df)
                    prow[df * 16 + l15] = f2bf(ab[df][jj]);
            }
        }
    }
}

// ---------------- reduce 8 slot-partials per token ----------------
__global__ __launch_bounds__(256) void slot_reduce_kernel(
    const u16* __restrict__ partial, u16* __restrict__ outq, float* __restrict__ outadd)
{
    int t = blockIdx.x, tid = threadIdx.x;
    int d0 = tid * 4;
    float s0 = 0.f, s1 = 0.f, s2 = 0.f, s3 = 0.f;
    #pragma unroll
    for (int s = 0; s < 8; ++s) {
        ushort4 u = *(const ushort4*)&partial[((size_t)t * 8 + s) * 1024 + d0];
        s0 += __uint_as_float((u32)u.x << 16);
        s1 += __uint_as_float((u32)u.y << 16);
        s2 += __uint_as_float((u32)u.z << 16);
        s3 += __uint_as_float((u32)u.w << 16);
    }
    if (outq) {
        int b = t >> 10, st = t & 1023;
        int head = d0 >> 6, dh = d0 & 63;
        ushort4 o;
        o.x = f2bf(s0); o.y = f2bf(s1); o.z = f2bf(s2); o.w = f2bf(s3);
        *(ushort4*)&outq[(((size_t)b * 16 + head) * 1024 + st) * 64 + dh] = o;
    } else {
        float* op = outadd + (size_t)t * 1024 + d0;
        float4 cur = *(const float4*)op;
        cur.x += s0; cur.y += s1; cur.z += s2; cur.w += s3;
        *(float4*)op = cur;
    }
}

// ---------------- fused slot-reduce for 3 attn gates -> Q/K/V ----------------
__global__ __launch_bounds__(256) void slot_reduce3_kernel(
    const u16* __restrict__ partial_base, size_t pstride, u16* __restrict__ qkvbase)
{
    int gy = blockIdx.y;
    const u16* partial = partial_base + (size_t)gy * pstride;
    u16* outq = qkvbase + (size_t)gy * NTOK * 1024;
    int t = blockIdx.x, tid = threadIdx.x;
    int d0 = tid * 4;
    float s0 = 0.f, s1 = 0.f, s2 = 0.f, s3 = 0.f;
    #pragma unroll
    for (int s = 0; s < 8; ++s) {
        ushort4 u = *(const ushort4*)&partial[((size_t)t * 8 + s) * 1024 + d0];
        s0 += __uint_as_float((u32)u.x << 16);
        s1 += __uint_as_float((u32)u.y << 16);
        s2 += __uint_as_float((u32)u.z << 16);
        s3 += __uint_as_float((u32)u.w << 16);
    }
    int b = t >> 10, st = t & 1023;
    int head = d0 >> 6, dh = d0 & 63;
    ushort4 o;
    o.x = f2bf(s0); o.y = f2bf(s1); o.z = f2bf(s2); o.w = f2bf(s3);
    *(ushort4*)&outq[(((size_t)b * 16 + head) * 1024 + st) * 64 + dh] = o;
}

// ---------------- nfreq partials + cprob partial sums ----------------
__global__ __launch_bounds__(256) void nfreq_partial_kernel(
    const int* __restrict__ gidx, const float* __restrict__ gval,
    const int* __restrict__ gcnt, const float* __restrict__ cprob,
    float* __restrict__ partials, float* __restrict__ cpart2)
{
    __shared__ float hist[8192];
    __shared__ float csum[4][64];
    int slice = blockIdx.x, gate = blockIdx.y;
    int N = (gate == 3) ? 8192 : 4096;
    int tid = threadIdx.x;
    int w = tid >> 6, lane = tid & 63;
    for (int i = tid; i < N; i += 256) hist[i] = 0.f;

    {
        const float* cp = cprob + (size_t)gate * NTOK * 64;
        float cs = 0.f;
        #pragma unroll
        for (int i = 0; i < 16; ++i) {
            int t = slice * 64 + i * 4 + w;
            cs += cp[(size_t)t * 64 + lane];
        }
        csum[w][lane] = cs;
    }
    __syncthreads();

    const int* gi = gidx + (size_t)gate * NTOK * CAP;
    const float* gv = gval + (size_t)gate * NTOK * CAP;
    const int* gc = gcnt + gate * NTOK;
    #pragma unroll 4
    for (int i = 0; i < 16; ++i) {
        int t = slice * 64 + i * 4 + w;
        int cnt = gc[t];
        for (int p = lane; p < cnt; p += 64) {
            int n = gi[(size_t)t * CAP + p];
            float v = gv[(size_t)t * CAP + p];
            atomicAdd(&hist[n], v);
        }
    }
    __syncthreads();
    float* op = partials + ((size_t)gate * 64 + slice) * 8192;
    for (int i = tid; i < N; i += 256) op[i] = hist[i];
    if (tid < 64)
        cpart2[((size_t)gate * 64 + slice) * 64 + tid] =
            csum[0][tid] + csum[1][tid] + csum[2][tid] + csum[3][tid];
}

// ---------------- aux: parallel reduce (84 blocks) ----------------
__global__ __launch_bounds__(256) void aux2_kernel(const float* __restrict__ partials,
                                                   const float* __restrict__ cpart2,
                                                   float* __restrict__ outp)
{
    __shared__ float red[4];
    __shared__ float cred[4][64];
    int bid = blockIdx.x, tid = threadIdx.x;
    float local = 0.f;
    if (bid < 80) {
        int gn = bid * 256 + tid;
        int gate = (gn < 12288) ? (gn >> 12) : 3;
        int ln = (gn < 12288) ? (gn & 4095) : (gn - 12288);
        const float* base = partials + (size_t)gate * 64 * 8192 + ln;
        float s = 0.f;
        #pragma unroll 8
        for (int c = 0; c < 64; ++c) s += base[(size_t)c * 8192];
        float Nf = (gate == 3) ? 8192.f : 4096.f;
        float f = s * (1.0f / 4096.0f);
        float d = f - 1.0f / Nf;
        local = d * d * Nf;
    } else {
        int gate = bid - 80;
        int w = tid >> 6, lane = tid & 63;
        const float* base = cpart2 + (size_t)gate * 64 * 64;
        float s = 0.f;
        #pragma unroll
        for (int i = 0; i < 16; ++i) s += base[(size_t)(i * 4 + w) * 64 + lane];
        cred[w][lane] = s;
        __syncthreads();
        if (tid < 64) {
            float tot = cred[0][tid] + cred[1][tid] + cred[2][tid] + cred[3][tid];
            float f = tot * (1.0f / 4096.0f);
            float d = f - (1.0f / 64.0f);
            local = d * d * 64.0f;
        }
    }
    #pragma unroll
    for (int o = 1; o < 64; o <<= 1) local += __shfl_xor(local, o);
    if ((tid & 63) == 0) red[tid >> 6] = local;
    __syncthreads();
    if (tid == 0) atomicAdd(outp, red[0] + red[1] + red[2] + red[3]);
}

// ---------------- MFMA flash attention, causal, d=64 — SPLIT-K partials ----------------
__global__ __launch_bounds__(256) void attn_split_kernel(const u16* __restrict__ Qb,
                                                         const u16* __restrict__ Kb,
                                                         const u16* __restrict__ Vb,
                                                         u16* __restrict__ Opart,
                                                         float2* __restrict__ mlb)
{
    __shared__ __align__(16) u32 VT[2048];
    __shared__ float csh[128];
    int qt = blockIdx.x;
    int bh = blockIdx.y;
    int z = blockIdx.z;
    int tid = threadIdx.x;
    int w = tid >> 6, lane = tid & 63;
    int hi = lane >> 5, l31 = lane & 31;
    int qb = qt * 128;
    int qcol = qb + w * 32 + l31;
    int wqmax = qb + w * 32 + 31;
    int kt0 = z * (qt + 1);
    int kt1 = kt0 + (qt + 1);

    const u16* Qbase = Qb + (size_t)bh * 1024 * 64;
    const u16* Kbase = Kb + (size_t)bh * 1024 * 64;
    const u16* Vbase = Vb + (size_t)bh * 1024 * 64;

    s16x8 qf[4];
    #pragma unroll
    for (int c = 0; c < 4; ++c)
        qf[c] = *(const s16x8*)&Qbase[(size_t)qcol * 64 + c * 16 + hi * 8];

    int vkey = 2 * (tid & 31);
    int vd = (tid >> 5) * 8;
    int base0 = kt0 * 64;
    uint4 va  = *(const uint4*)&Vbase[(size_t)(base0 + vkey) * 64 + vd];
    uint4 vb2 = *(const uint4*)&Vbase[(size_t)(base0 + vkey + 1) * 64 + vd];

    s16x8 kf[2][4];
    #pragma unroll
    for (int s = 0; s < 2; ++s)
        #pragma unroll
        for (int c = 0; c < 4; ++c)
            kf[s][c] = *(const s16x8*)&Kbase[(size_t)(base0 + s * 32 + l31) * 64 + c * 16 + hi * 8];

    float m = -3.0e38f, lden = 0.f;
    f32x16 oacc0, oacc1;
    #pragma unroll
    for (int r = 0; r < 16; ++r) { oacc0[r] = 0.f; oacc1[r] = 0.f; }

    for (int kt = kt0; kt < kt1; ++kt) {
        __syncthreads();
        {
            U16x8 ua, ub; ua.u = va; ub.u = vb2;
            #pragma unroll
            for (int j = 0; j < 8; ++j) {
                int d = vd + j;
                u32 pk = (u32)ua.s[j] | ((u32)ub.s[j] << 16);
                VT[(u32)((d * 32 + (tid & 31)) ^ ((d & 7) << 2))] = pk;
            }
        }
        __syncthreads();

        bool active = (kt * 64) <= wqmax;
        f32x16 s0, s1;
        if (active) {
            #pragma unroll
            for (int r = 0; r < 16; ++r) { s0[r] = 0.f; s1[r] = 0.f; }
            #pragma unroll
            for (int c = 0; c < 4; ++c) {
                s0 = MFMA32(kf[0][c], qf[c], s0);
                s1 = MFMA32(kf[1][c], qf[c], s1);
            }
        }
        if (kt + 1 < kt1) {
            int nb = (kt + 1) * 64;
            va  = *(const uint4*)&Vbase[(size_t)(nb + vkey) * 64 + vd];
            vb2 = *(const uint4*)&Vbase[(size_t)(nb + vkey + 1) * 64 + vd];
            if (nb <= wqmax) {
                #pragma unroll
                for (int s = 0; s < 2; ++s)
                    #pragma unroll
                    for (int c = 0; c < 4; ++c)
                        kf[s][c] = *(const s16x8*)&Kbase[(size_t)(nb + s * 32 + l31) * 64 + c * 16 + hi * 8];
            }
        }
        if (active) {
            float p0[16], p1[16];
            float pmax = -3.0e38f;
            #pragma unroll
            for (int r = 0; r < 16; ++r) {
                int crow = (r & 3) + 8 * (r >> 2) + 4 * hi;
                int k0 = kt * 64 + crow;
                float v0 = (k0 <= qcol) ? s0[r] * 0.125f : -3.0e38f;
                float v1 = (k0 + 32 <= qcol) ? s1[r] * 0.125f : -3.0e38f;
                p0[r] = v0; p1[r] = v1;
                pmax = fmaxf(pmax, fmaxf(v0, v1));
            }
            pmax = fmaxf(pmax, __shfl_xor(pmax, 32));
            float mn = fmaxf(m, pmax);
            float corr = __expf(m - mn);
            float rs = 0.f;
            #pragma unroll
            for (int r = 0; r < 16; ++r) {
                p0[r] = __expf(p0[r] - mn);
                p1[r] = __expf(p1[r] - mn);
                rs += p0[r] + p1[r];
            }
            rs += __shfl_xor(rs, 32);
            lden = lden * corr + rs;
            m = mn;
            if (hi == 0) csh[w * 32 + l31] = corr;
            float c16[16];
            #pragma unroll
            for (int r = 0; r < 16; ++r)
                c16[r] = csh[w * 32 + ((r & 3) + 8 * (r >> 2) + 4 * hi)];
            #pragma unroll
            for (int r = 0; r < 16; ++r) { oacc0[r] *= c16[r]; oacc1[r] *= c16[r]; }

            #pragma unroll
            for (int sub = 0; sub < 2; ++sub) {
                u32 e[8], x[8];
                #pragma unroll
                for (int j = 0; j < 8; ++j) {
                    float lo = sub ? p1[2 * j] : p0[2 * j];
                    float hi2 = sub ? p1[2 * j + 1] : p0[2 * j + 1];
                    e[j] = pkbf(lo, hi2);
                }
                #pragma unroll
                for (int j = 0; j < 8; ++j) x[j] = (u32)__shfl_xor((int)e[j], 32);
                Dw4 t0, t1;
                t0.d[0] = hi ? x[2] : e[0];
                t0.d[1] = hi ? x[3] : e[1];
                t0.d[2] = hi ? e[2] : x[0];
                t0.d[3] = hi ? e[3] : x[1];
                t1.d[0] = hi ? x[6] : e[4];
                t1.d[1] = hi ? x[7] : e[5];
                t1.d[2] = hi ? e[6] : x[4];
                t1.d[3] = hi ? e[7] : x[5];
                int kb0 = sub * 32 + hi * 8;
                int kb1 = kb0 + 16;
                int d0 = l31, d1 = 32 + l31;
                const char* vtb = (const char*)VT;
                s16x8 vf;
                vf = *(const s16x8*)(vtb + (((d0 * 128 + kb0 * 2)) ^ ((d0 & 7) << 4)));
                oacc0 = MFMA32(t0.v, vf, oacc0);
                vf = *(const s16x8*)(vtb + (((d1 * 128 + kb0 * 2)) ^ ((d1 & 7) << 4)));
                oacc1 = MFMA32(t0.v, vf, oacc1);
                vf = *(const s16x8*)(vtb + (((d0 * 128 + kb1 * 2)) ^ ((d0 & 7) << 4)));
                oacc0 = MFMA32(t1.v, vf, oacc0);
                vf = *(const s16x8*)(vtb + (((d1 * 128 + kb1 * 2)) ^ ((d1 & 7) << 4)));
                oacc1 = MFMA32(t1.v, vf, oacc1);
            }
        }
    }
    size_t pi = (size_t)(z * 8 + qt) * 64 + bh;
    if (hi == 0)
        mlb[pi * 128 + w * 32 + l31] = make_float2(m, lden);
    #pragma unroll
    for (int r = 0; r < 16; ++r) {
        int crow = (r & 3) + 8 * (r >> 2) + 4 * hi;
        u16* orow = Opart + (pi * 128 + w * 32 + crow) * 64;
        orow[l31]      = f2bf(oacc0[r]);
        orow[32 + l31] = f2bf(oacc1[r]);
    }
}

// ---------------- merge the 2 split partials -> attn_bf ----------------
__global__ __launch_bounds__(256) void attn_merge_kernel(const u16* __restrict__ Opart,
                                                         const float2* __restrict__ mlb,
                                                         u16* __restrict__ outbf)
{
    int t = blockIdx.x, tid = threadIdx.x;
    int b = t >> 10, s = t & 1023;
    int qt = s >> 7, qrow = s & 127;
    int hh = tid >> 4, q4 = (tid & 15) * 4;
    size_t pi0 = (size_t)qt * 64 + (b * 16 + hh);
    size_t pi1 = (size_t)(8 + qt) * 64 + (b * 16 + hh);
    float2 ml0 = mlb[pi0 * 128 + qrow];
    float2 ml1 = mlb[pi1 * 128 + qrow];
    float M = fmaxf(ml0.x, ml1.x);
    float w0 = __expf(ml0.x - M);
    float w1 = __expf(ml1.x - M);
    float inv = 1.0f / (ml0.y * w0 + ml1.y * w1);
    ushort4 a = *(const ushort4*)&Opart[(pi0 * 128 + qrow) * 64 + q4];
    ushort4 c = *(const ushort4*)&Opart[(pi1 * 128 + qrow) * 64 + q4];
    ushort4 o;
    o.x = f2bf((bf2f(a.x) * w0 + bf2f(c.x) * w1) * inv);
    o.y = f2bf((bf2f(a.y) * w0 + bf2f(c.y) * w1) * inv);
    o.z = f2bf((bf2f(a.z) * w0 + bf2f(c.z) * w1) * inv);
    o.w = f2bf((bf2f(a.w) * w0 + bf2f(c.w) * w1) * inv);
    *(ushort4*)&outbf[(size_t)t * 1024 + hh * 64 + q4] = o;
}

extern "C" void kernel_launch(void* const* d_in, const int* in_sizes, int n_in,
                              void* d_out, int out_size, void* d_ws, size_t ws_size,
                              hipStream_t stream) {
    const float* x            = (const float*)d_in[0];
    const float* neuron_emb   = (const float*)d_in[1];
    const float* proj_attn_k  = (const float*)d_in[2];
    const float* proj_attn_b  = (const float*)d_in[3];
    const float* tau_attn_k   = (const float*)d_in[4];
    const float* tau_attn_b   = (const float*)d_in[5];
    const float* proj_know_k  = (const float*)d_in[6];
    const float* proj_know_b  = (const float*)d_in[7];
    const float* tau_know_k   = (const float*)d_in[8];
    const float* tau_know_b   = (const float*)d_in[9];
    const float* cluster_qk   = (const float*)d_in[10];
    const float* cluster_v    = (const float*)d_in[11];
    const float* cluster_know = (const float*)d_in[12];
    const float* qk_neurons   = (const float*)d_in[13];
    const float* v_neurons    = (const float*)d_in[14];
    const float* know_neurons = (const float*)d_in[15];
    const float* expand_O     = (const float*)d_in[16];
    const float* ln1_s        = (const float*)d_in[17];
    const float* ln1_b        = (const float*)d_in[18];
    const float* ln2_s        = (const float*)d_in[19];
    const float* ln2_b        = (const float*)d_in[20];
    float* out = (float*)d_out;

    char* wsb = (char*)d_ws;
    size_t off = 0;
    auto alloc = [&](size_t bytes) -> void* {
        void* p = wsb + off;
        off = (off + bytes + 255) & ~(size_t)255;
        return p;
    };
    u16*   emb16    = (u16*)alloc((size_t)16384 * 128 * 2);
    float* ce_norm  = (float*)alloc((size_t)3 * 64 * 128 * 4);
    u16*   nbf      = (u16*)alloc((size_t)16384 * 1024 * 2);
    float* h1       = (float*)alloc((size_t)NTOK * 1024 * 4);
    u16*   h1bf     = (u16*)alloc((size_t)NTOK * 1024 * 2);
    float* h_all    = (float*)alloc((size_t)NTOK * 384 * 4);
    float* tau_all  = (float*)alloc((size_t)NTOK * 3 * 4);
    u16*   hgbf     = (u16*)alloc((size_t)4 * NTOK * 128 * 2);
    int*   gidx     = (int*)alloc((size_t)4 * NTOK * CAP * 4);
    float* gvalp    = (float*)alloc((size_t)4 * NTOK * CAP * 4);
    int*   gcnt     = (int*)alloc((size_t)4 * NTOK * 4);
    int*   topcg    = (int*)alloc((size_t)4 * NTOK * 8 * 4);
    float* Wattn    = (float*)alloc((size_t)3 * NTOK * 512 * 4);
    u32*   entries  = (u32*)alloc((size_t)4 * 40960 * 4);
    u32*   tiletab  = (u32*)alloc((size_t)4 * 640 * 4);
    int*   ntiles   = (int*)alloc((size_t)4 * 4);
    u16*   qkv      = (u16*)alloc((size_t)3 * NTOK * 1024 * 2);
    u16*   projA_t  = (u16*)alloc((size_t)384 * 1024 * 2);
    u16*   know_t   = (u16*)alloc((size_t)128 * 1024 * 2);
    u16*   exp_t    = (u16*)alloc((size_t)1024 * 1024 * 2);
    float* cprob    = (float*)alloc((size_t)4 * NTOK * 64 * 4);
    float* cpart2   = (float*)alloc((size_t)4 * 64 * 64 * 4);
    u16*   spartial = (u16*)alloc((size_t)NTOK * 8 * 1024 * 2);
    u16*   Opart    = (u16*)alloc((size_t)2 * 8 * 64 * 128 * 64 * 2);
    float2* mlb     = (float2*)alloc((size_t)2 * 8 * 64 * 128 * 8);
    // two extra spartial buffers for the fused attn sense path (guarded by ws_size)
    const size_t SPSTRIDE = (size_t)NTOK * 8 * 1024;   // elements (u16)
    alloc(SPSTRIDE * 2);   // spartial gate 1
    alloc(SPSTRIDE * 2);   // spartial gate 2
    bool fused = (off <= ws_size);

    float* h_know   = h_all;
    float* tau_kn   = tau_all;
    float* Wknow    = Wattn;
    float* partials = Wattn + (size_t)NTOK * 1024;
    u16* ntT_qk   = (u16*)h1;
    u16* ntT_v    = (u16*)h1 + (size_t)4096 * 1024;
    u16* ntT_know = (u16*)h1;

    u16* Qbuf = qkv;
    u16* Kbuf = qkv + (size_t)NTOK * 1024;
    u16* Vbuf = qkv + (size_t)2 * NTOK * 1024;
    u16* attn_bf = h1bf;

    hipMemsetAsync(out + (size_t)NTOK * 1024, 0, 4, stream);

    norm_rows_kernel<<<16384 / 4, 256, 0, stream>>>(neuron_emb, emb16, nullptr, 16384);
    norm_rows_kernel<<<16, 256, 0, stream>>>(cluster_qk, nullptr, ce_norm, 64);
    norm_rows_kernel<<<16, 256, 0, stream>>>(cluster_v, nullptr, ce_norm + 64 * 128, 64);
    norm_rows_kernel<<<16, 256, 0, stream>>>(cluster_know, nullptr, ce_norm + 2 * 64 * 128, 64);
    cast_bf16_kernel<<<4096, 256, 0, stream>>>(qk_neurons, nbf, 4096 * 1024);
    cast_bf16_kernel<<<4096, 256, 0, stream>>>(v_neurons, nbf + (size_t)4096 * 1024, 4096 * 1024);
    cast_bf16_kernel<<<8192, 256, 0, stream>>>(know_neurons, nbf + (size_t)8192 * 1024, 8192 * 1024);
    transpose_cast_kernel<<<dim3(6, 16), dim3(64, 4), 0, stream>>>(proj_attn_k, projA_t, 384, 1024);
    transpose_cast_kernel<<<dim3(2, 16), dim3(64, 4), 0, stream>>>(proj_know_k, know_t, 128, 1024);
    transpose_cast_kernel<<<dim3(16, 16), dim3(64, 4), 0, stream>>>(expand_O, exp_t, 1024, 1024);

    ln_kernel<<<NTOK, 256, 0, stream>>>(x, ln1_s, ln1_b, h1, h1bf);
    gemm_mfma_kernel<<<dim3(3, 32), 256, 0, stream>>>(h1bf, projA_t, proj_attn_b, nullptr, h_all, 384, 1024);
    vecproj_kernel<<<NTOK, 64, 0, stream>>>(h1, tau_attn_k, tau_attn_b, tau_all, 3);
    ntab_transpose_kernel<<<dim3(64, 16, 1), dim3(64, 4), 0, stream>>>(nbf, ntT_qk, 64);
    ntab_transpose_kernel<<<dim3(64, 16, 1), dim3(64, 4), 0, stream>>>(
        nbf + (size_t)4096 * 1024, ntT_v, 64);

    cluster_kernel<<<dim3(NTOK / 32, 3), 256, 0, stream>>>(h_all, 384, ce_norm, cprob, topcg, 0);
    listbuild_kernel<<<3, 1024, 0, stream>>>(topcg, entries, tiletab, ntiles);
    cast_gateh_kernel<<<NTOK, 256, 0, stream>>>(h_all, 384, 3, hgbf);
    score_bs_kernel<64><<<dim3(640, 3), 256, 0, stream>>>(hgbf, emb16, Wattn, entries, tiletab, ntiles);
    gate_select_kernel<512, 6><<<dim3(1024, 3), 256, 0, stream>>>(
        Wattn, tau_all, 3, topcg, gidx, gvalp, gcnt, 0);

    if (fused) {
        sense_bs_attn_kernel<<<dim3(640, 3), 256, 0, stream>>>(
            h1bf, nbf, ntT_qk, nbf + (size_t)4096 * 1024, ntT_v,
            Wattn, entries, tiletab, ntiles, spartial, SPSTRIDE, 0);
        slot_reduce3_kernel<<<dim3(NTOK, 3), 256, 0, stream>>>(spartial, SPSTRIDE, qkv);
    } else {
        for (int g = 0; g < 3; ++g) {
            sense_bs_attn_kernel<<<dim3(640, 1), 256, 0, stream>>>(
                h1bf, nbf, ntT_qk, nbf + (size_t)4096 * 1024, ntT_v,
                Wattn, entries, tiletab, ntiles, spartial, 0, g);
            u16* outq = (g == 0) ? Qbuf : (g == 1) ? Kbuf : Vbuf;
            slot_reduce_kernel<<<NTOK, 256, 0, stream>>>(spartial, outq, nullptr);
        }
    }

    attn_split_kernel<<<dim3(8, 64, 2), 256, 0, stream>>>(Qbuf, Kbuf, Vbuf, Opart, mlb);
    attn_merge_kernel<<<NTOK, 256, 0, stream>>>(Opart, mlb, attn_bf);
    gemm_mfma_kernel<<<dim3(8, 32), 256, 0, stream>>>(attn_bf, exp_t, nullptr, x, out, 1024, 1024);

    ln_kernel<<<NTOK, 256, 0, stream>>>(out, ln2_s, ln2_b, h1, h1bf);
    gemm_mfma_kernel<<<dim3(1, 32), 256, 0, stream>>>(h1bf, know_t, proj_know_b, nullptr, h_know, 128, 1024);
    vecproj_kernel<<<NTOK, 64, 0, stream>>>(h1, tau_know_k, tau_know_b, tau_kn, 1);
    ntab_transpose_kernel<<<dim3(64, 16, 2), dim3(64, 4), 0, stream>>>(
        nbf + (size_t)8192 * 1024, ntT_know, 128);

    cluster_kernel<<<dim3(NTOK / 32, 1), 256, 0, stream>>>(h_know, 128, ce_norm + 2 * 64 * 128,
                                                           cprob, topcg, 3);
    listbuild_kernel<<<1, 1024, 0, stream>>>(topcg + (size_t)3 * NTOK * 8,
                                             entries + (size_t)3 * 40960,
                                             tiletab + (size_t)3 * 640, ntiles + 3);
    cast_gateh_kernel<<<NTOK, 256, 0, stream>>>(h_know, 128, 1, hgbf + (size_t)3 * NTOK * 128);
    score_bs_kernel<128><<<dim3(640, 1), 256, 0, stream>>>(
        hgbf + (size_t)3 * NTOK * 128, emb16 + (size_t)8192 * 128, Wknow,
        entries + (size_t)3 * 40960, tiletab + (size_t)3 * 640, ntiles + 3);
    gate_select_kernel<1024, 7><<<dim3(1024, 1), 256, 0, stream>>>(
        Wknow, tau_kn, 1, topcg, gidx, gvalp, gcnt, 3);
    sense_bs_kernel<128><<<640, 256, 0, stream>>>(
        h1bf, nbf + (size_t)8192 * 1024, ntT_know, Wknow,
        entries + (size_t)3 * 40960, tiletab + (size_t)3 * 640, ntiles + 3, spartial);
    slot_reduce_kernel<<<NTOK, 256, 0, stream>>>(spartial, nullptr, out);

    nfreq_partial_kernel<<<dim3(64, 4), 256, 0, stream>>>(gidx, gvalp, gcnt, cprob, partials, cpart2);
    aux2_kernel<<<84, 256, 0, stream>>>(partials, cpart2, out + (size_t)NTOK * 1024);
}

// Round 20
// 701.489 us; speedup vs baseline: 1.0330x; 1.0330x over previous
//
#include <hip/hip_runtime.h>

typedef unsigned short u16;
typedef unsigned int u32;
typedef unsigned long long u64;
typedef __attribute__((ext_vector_type(8))) short s16x8;
typedef __attribute__((ext_vector_type(4))) float f32x4;
typedef __attribute__((ext_vector_type(16))) float f32x16;

#define NTOK 4096
#define CAP 144

#define MFMA32(a,b,c) __builtin_amdgcn_mfma_f32_32x32x16_bf16(a,b,c,0,0,0)
#define MFMA16(a,b,c) __builtin_amdgcn_mfma_f32_16x16x32_bf16(a,b,c,0,0,0)

union U16x8 { uint4 u; u16 s[8]; };
union Dw4 { u32 d[4]; s16x8 v; };

__device__ __forceinline__ u16 f2bf(float f) {
    u32 u = __float_as_uint(f);
    u32 r = u + 0x7FFFu + ((u >> 16) & 1u);
    return (u16)(r >> 16);
}
__device__ __forceinline__ float bf2f(u16 v) { return __uint_as_float((u32)v << 16); }
__device__ __forceinline__ u32 pkbf(float lo, float hi) {
    u32 r;
    asm("v_cvt_pk_bf16_f32 %0, %1, %2" : "=v"(r) : "v"(lo), "v"(hi));
    return r;
}
__device__ __forceinline__ u32 mapkey(float f) {
    u32 b = __float_as_uint(f);
    return (b & 0x80000000u) ? ~b : (b | 0x80000000u);
}
// async global->LDS DMA, 16B per lane; LDS dest = wave-uniform base + lane*16
__device__ __forceinline__ void gload16(const void* g, void* l) {
    __builtin_amdgcn_global_load_lds(
        (__attribute__((address_space(1))) const void*)g,
        (__attribute__((address_space(3))) void*)l, 16, 0, 0);
}

// ---------------- row L2-normalize (128-wide rows) -> bf16 rows and/or f32 rows ----------------
__global__ __launch_bounds__(256) void norm_rows_kernel(const float* __restrict__ in,
                                                        u16* __restrict__ out16,
                                                        float* __restrict__ outRow, int rows)
{
    int row = blockIdx.x * 4 + (threadIdx.x >> 6);
    int lane = threadIdx.x & 63;
    if (row >= rows) return;
    float2 v = *(const float2*)&in[(size_t)row * 128 + lane * 2];
    float ss = v.x * v.x + v.y * v.y;
    #pragma unroll
    for (int o = 1; o < 64; o <<= 1) ss += __shfl_xor(ss, o);
    float rn = 1.0f / (sqrtf(ss) + 1e-8f);
    float2 ov = make_float2(v.x * rn, v.y * rn);
    if (out16)
        *(u32*)&out16[(size_t)row * 128 + lane * 2] = pkbf(ov.x, ov.y);
    if (outRow)
        *(float2*)&outRow[(size_t)row * 128 + lane * 2] = ov;
}

// ---------------- f32 -> bf16 cast ----------------
__global__ __launch_bounds__(256) void cast_bf16_kernel(const float* __restrict__ in,
                                                        u16* __restrict__ out, int n)
{
    int i = (blockIdx.x * 256 + threadIdx.x) * 4;
    if (i >= n) return;
    float4 v = *(const float4*)&in[i];
    ushort4 o;
    o.x = f2bf(v.x); o.y = f2bf(v.y); o.z = f2bf(v.z); o.w = f2bf(v.w);
    *(ushort4*)&out[i] = o;
}

// ---------------- gate-h bf16 rows ----------------
__global__ __launch_bounds__(256) void cast_gateh_kernel(const float* __restrict__ h, int stride,
                                                         int ngates, u16* __restrict__ out)
{
    int t = blockIdx.x, tid = threadIdx.x;
    int total = ngates * 128;
    for (int i = tid; i < total; i += 256) {
        int g = i >> 7, d = i & 127;
        out[(size_t)g * NTOK * 128 + (size_t)t * 128 + d] = f2bf(h[(size_t)t * stride + i]);
    }
}

// ---------------- transpose + cast: in f32 [Kk][Nn] -> out bf16 [Nn][Kk] ----------------
__global__ void transpose_cast_kernel(const float* __restrict__ in, u16* __restrict__ out,
                                      int Nn, int Kk)
{
    __shared__ float sT[64][65];
    int n0 = blockIdx.x * 64, k0 = blockIdx.y * 64;
    int tx = threadIdx.x, ty = threadIdx.y;
    #pragma unroll
    for (int r = 0; r < 64; r += 4)
        sT[ty + r][tx] = in[(size_t)(k0 + ty + r) * Nn + n0 + tx];
    __syncthreads();
    #pragma unroll
    for (int r = 0; r < 64; r += 4)
        out[(size_t)(n0 + ty + r) * Kk + k0 + tx] = f2bf(sT[tx][ty + r]);
}

// ---------------- per-cluster bf16 transpose: in [c][j][1024] -> out [c][d][NCLv] ----------------
__global__ void ntab_transpose_kernel(const u16* __restrict__ in, u16* __restrict__ out, int NCLv)
{
    __shared__ u16 tile[64][65];
    int cc = blockIdx.x, db = blockIdx.y * 64, jb = blockIdx.z * 64;
    int tx = threadIdx.x, ty = threadIdx.y;
    const u16* src = in + (size_t)cc * NCLv * 1024;
    #pragma unroll
    for (int r = 0; r < 64; r += 4)
        tile[ty + r][tx] = src[(size_t)(jb + ty + r) * 1024 + db + tx];
    __syncthreads();
    u16* dst = out + (size_t)cc * NCLv * 1024;
    #pragma unroll
    for (int r = 0; r < 64; r += 4)
        dst[(size_t)(db + ty + r) * NCLv + jb + tx] = tile[tx][ty + r];
}

// ---------------- LayerNorm (+fused bf16 copy) ----------------
__global__ __launch_bounds__(256) void ln_kernel(const float* __restrict__ x,
                                                 const float* __restrict__ gam,
                                                 const float* __restrict__ bet,
                                                 float* __restrict__ out,
                                                 u16* __restrict__ outbf)
{
    __shared__ float red[8];
    int t = blockIdx.x, tid = threadIdx.x;
    const float* row = x + (size_t)t * 1024;
    float4 v = *(const float4*)&row[tid * 4];
    float s = v.x + v.y + v.z + v.w;
    #pragma unroll
    for (int o = 1; o < 64; o <<= 1) s += __shfl_xor(s, o);
    if ((tid & 63) == 0) red[tid >> 6] = s;
    __syncthreads();
    float mean = (red[0] + red[1] + red[2] + red[3]) * (1.0f / 1024.0f);
    float d0 = v.x - mean, d1 = v.y - mean, d2 = v.z - mean, d3 = v.w - mean;
    float ss = d0 * d0 + d1 * d1 + d2 * d2 + d3 * d3;
    #pragma unroll
    for (int o = 1; o < 64; o <<= 1) ss += __shfl_xor(ss, o);
    if ((tid & 63) == 0) red[4 + (tid >> 6)] = ss;
    __syncthreads();
    float var = (red[4] + red[5] + red[6] + red[7]) * (1.0f / 1024.0f);
    float rstd = 1.0f / sqrtf(var + 1e-6f);
    int d = tid * 4;
    float4 g4 = *(const float4*)&gam[d];
    float4 b4 = *(const float4*)&bet[d];
    float4 o4;
    o4.x = d0 * rstd * g4.x + b4.x;
    o4.y = d1 * rstd * g4.y + b4.y;
    o4.z = d2 * rstd * g4.z + b4.z;
    o4.w = d3 * rstd * g4.w + b4.w;
    *(float4*)&out[(size_t)t * 1024 + d] = o4;
    if (outbf) {
        ushort4 ob;
        ob.x = f2bf(o4.x); ob.y = f2bf(o4.y); ob.z = f2bf(o4.z); ob.w = f2bf(o4.w);
        *(ushort4*)&outbf[(size_t)t * 1024 + d] = ob;
    }
}

// ---------------- bf16 MFMA GEMM ----------------
__global__ __launch_bounds__(256) void gemm_mfma_kernel(const u16* __restrict__ A,
                                                        const u16* __restrict__ Bt,
                                                        const float* __restrict__ bias,
                                                        const float* __restrict__ resid,
                                                        float* __restrict__ C, int N, int K)
{
    __shared__ __align__(16) u16 sA[128 * 80];
    __shared__ __align__(16) u16 sB[128 * 80];
    int n0 = blockIdx.x * 128, m0 = blockIdx.y * 128;
    int tid = threadIdx.x;
    int l = tid & 63, wid = tid >> 6;
    int wm = wid >> 1, wn = wid & 1;
    int l15 = l & 15, hi4 = l >> 4;
    f32x4 acc[4][4];
    #pragma unroll
    for (int i = 0; i < 4; ++i)
        #pragma unroll
        for (int j = 0; j < 4; ++j)
            #pragma unroll
            for (int q = 0; q < 4; ++q) acc[i][j][q] = 0.f;

    int sr = tid >> 1, scb = (tid & 1) * 4;
    for (int k0 = 0; k0 < K; k0 += 64) {
        __syncthreads();
        #pragma unroll
        for (int j = 0; j < 4; ++j) {
            int ch = scb + j;
            uint4 va = *(const uint4*)&A[(size_t)(m0 + sr) * K + k0 + ch * 8];
            *(uint4*)&sA[sr * 80 + ch * 8] = va;
            uint4 vb = *(const uint4*)&Bt[(size_t)(n0 + sr) * K + k0 + ch * 8];
            *(uint4*)&sB[sr * 80 + ch * 8] = vb;
        }
        __syncthreads();
        #pragma unroll
        for (int kc = 0; kc < 2; ++kc) {
            s16x8 af[4], bf[4];
            #pragma unroll
            for (int mf = 0; mf < 4; ++mf)
                af[mf] = *(const s16x8*)&sA[(wm * 64 + mf * 16 + l15) * 80 + kc * 32 + hi4 * 8];
            #pragma unroll
            for (int nf = 0; nf < 4; ++nf)
                bf[nf] = *(const s16x8*)&sB[(wn * 64 + nf * 16 + l15) * 80 + kc * 32 + hi4 * 8];
            #pragma unroll
            for (int mf = 0; mf < 4; ++mf)
                #pragma unroll
                for (int nf = 0; nf < 4; ++nf)
                    acc[mf][nf] = MFMA16(af[mf], bf[nf], acc[mf][nf]);
        }
    }
    #pragma unroll
    for (int mf = 0; mf < 4; ++mf)
        #pragma unroll
        for (int nf = 0; nf < 4; ++nf)
            #pragma unroll
            for (int j = 0; j < 4; ++j) {
                int row = m0 + wm * 64 + mf * 16 + hi4 * 4 + j;
                int col = n0 + wn * 64 + nf * 16 + l15;
                float v = acc[mf][nf][j];
                if (bias) v += bias[col];
                if (resid) v += resid[(size_t)row * N + col];
                C[(size_t)row * N + col] = v;
            }
}

// ---------------- tiny projection ----------------
__global__ __launch_bounds__(64) void vecproj_kernel(const float* __restrict__ h,
                                                     const float* __restrict__ W,
                                                     const float* __restrict__ bias,
                                                     float* __restrict__ out, int nw)
{
    int t = blockIdx.x, lane = threadIdx.x;
    float p0 = 0.f, p1 = 0.f, p2 = 0.f;
    #pragma unroll
    for (int it = 0; it < 4; ++it) {
        int d = it * 256 + lane * 4;
        float4 h4 = *(const float4*)&h[(size_t)t * 1024 + d];
        if (nw == 1) {
            float4 w4 = *(const float4*)&W[d];
            p0 += h4.x * w4.x + h4.y * w4.y + h4.z * w4.z + h4.w * w4.w;
        } else {
            float4 w0 = *(const float4*)&W[d * 3];
            float4 w1 = *(const float4*)&W[d * 3 + 4];
            float4 w2 = *(const float4*)&W[d * 3 + 8];
            p0 += h4.x * w0.x + h4.y * w0.w + h4.z * w1.z + h4.w * w2.y;
            p1 += h4.x * w0.y + h4.y * w1.x + h4.z * w1.w + h4.w * w2.z;
            p2 += h4.x * w0.z + h4.y * w1.y + h4.z * w2.x + h4.w * w2.w;
        }
    }
    #pragma unroll
    for (int o = 1; o < 64; o <<= 1) {
        p0 += __shfl_xor(p0, o);
        p1 += __shfl_xor(p1, o);
        p2 += __shfl_xor(p2, o);
    }
    if (lane == 0) {
        out[(size_t)t * nw + 0] = p0 + bias[0];
        if (nw > 1) out[(size_t)t * nw + 1] = p1 + bias[1];
        if (nw > 2) out[(size_t)t * nw + 2] = p2 + bias[2];
    }
}

// ---------------- cluster scores + softmax(cprob) + top-8, tiled f32 ----------------
__global__ __launch_bounds__(256) void cluster_kernel(
    const float* __restrict__ hsrc, int hstride,
    const float* __restrict__ cebase,
    float* __restrict__ cprob, int* __restrict__ topcg, int gate_base)
{
    __shared__ float sH[32 * 136];
    __shared__ float sC[64 * 136];
    int gy = blockIdx.y;
    const float* ce = cebase + (size_t)(gy >> 1) * (64 * 128);
    int hoff = gy * 128;
    int gout = gate_base + gy;
    int t0 = blockIdx.x * 32;
    int tid = threadIdx.x;

    {
        int r = tid >> 3, c0 = (tid & 7) * 16;
        const float* src = hsrc + (size_t)(t0 + r) * hstride + hoff + c0;
        #pragma unroll
        for (int q = 0; q < 16; q += 4)
            *(float4*)&sH[r * 136 + c0 + q] = *(const float4*)&src[q];
    }
    {
        int r = tid >> 2, c0 = (tid & 3) * 32;
        const float* src = ce + (size_t)r * 128 + c0;
        #pragma unroll
        for (int q = 0; q < 32; q += 4)
            *(float4*)&sC[r * 136 + c0 + q] = *(const float4*)&src[q];
    }
    __syncthreads();

    int tt = tid >> 3, cl0 = tid & 7;
    float acc[8] = {};
    for (int d4 = 0; d4 < 128; d4 += 4) {
        float4 hv = *(const float4*)&sH[tt * 136 + d4];
        #pragma unroll
        for (int c8 = 0; c8 < 8; ++c8) {
            float4 cv = *(const float4*)&sC[(cl0 + 8 * c8) * 136 + d4];
            acc[c8] = fmaf(hv.x, cv.x, acc[c8]);
            acc[c8] = fmaf(hv.y, cv.y, acc[c8]);
            acc[c8] = fmaf(hv.z, cv.z, acc[c8]);
            acc[c8] = fmaf(hv.w, cv.w, acc[c8]);
        }
    }
    __syncthreads();
    float* sS = sH;
    #pragma unroll
    for (int c8 = 0; c8 < 8; ++c8)
        sS[tt * 72 + cl0 + 8 * c8] = acc[c8];
    __syncthreads();

    int w = tid >> 6, lane = tid & 63;
    for (int k = 0; k < 8; ++k) {
        int t = w * 8 + k;
        float s = sS[t * 72 + lane];
        float mx = s;
        #pragma unroll
        for (int o = 1; o < 64; o <<= 1) mx = fmaxf(mx, __shfl_xor(mx, o));
        float e = expf(s - mx);
        float sm = e;
        #pragma unroll
        for (int o = 1; o < 64; o <<= 1) sm += __shfl_xor(sm, o);
        cprob[((size_t)gout * NTOK + t0 + t) * 64 + lane] = e / sm;
        int rank = 0;
        for (int j = 0; j < 64; ++j) {
            float sj = sS[t * 72 + j];
            rank += (sj > s || (sj == s && j < lane)) ? 1 : 0;
        }
        if (rank < 8) topcg[((size_t)gout * NTOK + t0 + t) * 8 + rank] = lane;
    }
}

// ---------------- build per-cluster padded (t,s) entry lists + 64-entry tile table ----------------
__global__ __launch_bounds__(1024) void listbuild_kernel(
    const int* __restrict__ topc_base, u32* __restrict__ entries_base,
    u32* __restrict__ tiletab_base, int* __restrict__ ntiles_base)
{
    __shared__ int cnt[64], offp[64], woff[64], tbase[64];
    int g = blockIdx.x;
    const int* tc = topc_base + (size_t)g * NTOK * 8;
    u32* eg = entries_base + (size_t)g * 40960;
    u32* tt = tiletab_base + (size_t)g * 640;
    int tid = threadIdx.x;
    if (tid < 64) { cnt[tid] = 0; woff[tid] = 0; }
    __syncthreads();
    int myc[32];
    #pragma unroll
    for (int i = 0; i < 32; ++i) {
        int t = tid * 4 + (i >> 3), s = i & 7;
        int c = tc[(size_t)t * 8 + s] & 63;
        myc[i] = c;
        atomicAdd(&cnt[c], 1);
    }
    __syncthreads();
    if (tid < 64) {
        int pc = (cnt[tid] + 63) & ~63;
        int sum = pc;
        #pragma unroll
        for (int o = 1; o < 64; o <<= 1) { int up = __shfl_up(sum, o); if (tid >= o) sum += up; }
        offp[tid] = sum - pc;
        int nt = pc >> 6;
        int tsum = nt;
        #pragma unroll
        for (int o = 1; o < 64; o <<= 1) { int up = __shfl_up(tsum, o); if (tid >= o) tsum += up; }
        tbase[tid] = tsum - nt;
        if (tid == 63) ntiles_base[g] = tsum;
    }
    __syncthreads();
    int totpad = offp[63] + ((cnt[63] + 63) & ~63);
    for (int i = tid; i < totpad; i += 1024) eg[i] = 0xFFFFFFFFu;
    __syncthreads();
    #pragma unroll
    for (int i = 0; i < 32; ++i) {
        int t = tid * 4 + (i >> 3), s = i & 7;
        int c = myc[i];
        int pos = offp[c] + atomicAdd(&woff[c], 1);
        eg[pos] = (u32)t | ((u32)s << 12);
    }
    __syncthreads();
    if (tid < 64) {
        int nt = ((cnt[tid] + 63) & ~63) >> 6;
        int eb = offp[tid] >> 6;
        for (int k2 = 0; k2 < nt; ++k2)
            tt[tbase[tid] + k2] = ((u32)tid << 16) | (u32)(eb + k2);
    }
}

// ---------------- block-sparse gate scoring (XCD-swizzled tiles) ----------------
template<int NCL>
__global__ __launch_bounds__(256) void score_bs_kernel(
    const u16* __restrict__ hgbf,
    const u16* __restrict__ embbase,
    float* __restrict__ scsbase,
    const u32* __restrict__ entries,
    const u32* __restrict__ tiletab,
    const int* __restrict__ ntiles)
{
    constexpr int NFR = NCL / 16;
    __shared__ __align__(16) u16 sH[64 * 136];
    __shared__ __align__(16) u16 sE[NCL * 136];
    __shared__ u32 ent[64];
    int gy = blockIdx.y;
    int bsw = ((int)blockIdx.x & 7) * 80 + ((int)blockIdx.x >> 3);
    if (bsw >= ntiles[gy]) return;
    u32 te = tiletab[(size_t)gy * 640 + bsw];
    int c = (int)(te >> 16) & 63;
    int e0 = (int)(te & 0x3FFu) * 64;
    const u32* eg = entries + (size_t)gy * 40960;
    const u16* Hg = hgbf + (size_t)gy * NTOK * 128;
    const u16* emb = embbase + (size_t)(gy >> 1) * 4096 * 128 + (size_t)c * NCL * 128;
    float* scs = scsbase + (size_t)gy * NTOK * (8 * NCL);

    int tid = threadIdx.x;
    int w = tid >> 6, lane = tid & 63;
    int l15 = lane & 15, hi4 = lane >> 4;

    if (tid < 64) ent[tid] = eg[e0 + tid];
    __syncthreads();

    #pragma unroll
    for (int u = 0; u < 4; ++u) {
        int idx = tid + u * 256;
        int r = idx >> 4, cq = idx & 15;
        int t = (int)(ent[r] & 4095u);
        uint4 v = *(const uint4*)&Hg[(size_t)t * 128 + cq * 8];
        *(uint4*)&sH[r * 136 + cq * 8] = v;
    }
    #pragma unroll
    for (int u = 0; u < NCL / 16; ++u) {
        int idx = tid + u * 256;
        int r = idx >> 4, cq = idx & 15;
        uint4 v = *(const uint4*)&emb[(size_t)r * 128 + cq * 8];
        *(uint4*)&sE[r * 136 + cq * 8] = v;
    }
    __syncthreads();

    f32x4 acc[NFR];
    #pragma unroll
    for (int nf = 0; nf < NFR; ++nf) { acc[nf][0] = 0.f; acc[nf][1] = 0.f; acc[nf][2] = 0.f; acc[nf][3] = 0.f; }
    #pragma unroll
    for (int kc = 0; kc < 4; ++kc) {
        s16x8 af = *(const s16x8*)&sH[(w * 16 + l15) * 136 + kc * 32 + hi4 * 8];
        #pragma unroll
        for (int nf = 0; nf < NFR; ++nf) {
            s16x8 bf = *(const s16x8*)&sE[(nf * 16 + l15) * 136 + kc * 32 + hi4 * 8];
            acc[nf] = MFMA16(af, bf, acc[nf]);
        }
    }

    int row0 = w * 16 + hi4 * 4;
    #pragma unroll
    for (int jj = 0; jj < 4; ++jj) {
        u32 e = ent[row0 + jj];
        if (e != 0xFFFFFFFFu) {
            int t = (int)(e & 4095u), s = (int)((e >> 12) & 7u);
            float* orow = scs + (size_t)t * (8 * NCL) + s * NCL;
            #pragma unroll
            for (int nf = 0; nf < NFR; ++nf)
                orow[nf * 16 + l15] = acc[nf][jj];
        }
    }
}

// ---------------- gate select over precomputed dense scores ----------------
template<int NCAND, int LGCS>
__global__ __launch_bounds__(256) void gate_select_kernel(
    float* __restrict__ scsg,
    const float* __restrict__ tausrc, int taustride,
    const int* __restrict__ topcg,
    int* __restrict__ gidx, float* __restrict__ gval, int* __restrict__ gcnt,
    int gate_base)
{
    constexpr int CSM = (1 << LGCS) - 1;
    __shared__ float lds_scs[4][NCAND];
    __shared__ int   lds_hist[4][256];
    __shared__ int   lds_topc[4][8];
    __shared__ float lds_keg[4][CAP];

    int gy = blockIdx.y;
    int gg = gate_base + gy;
    int tauoff = gy;
    const int* tsrc = topcg + (size_t)gg * NTOK * 8;
    float* scs = scsg + (size_t)gy * NTOK * NCAND;
    gidx += (size_t)gg * NTOK * CAP;
    gval += (size_t)gg * NTOK * CAP;
    gcnt += gg * NTOK;

    int w = threadIdx.x >> 6, lane = threadIdx.x & 63;
    int t = blockIdx.x * 4 + w;

    float* srow = scs + (size_t)t * NCAND;
    #pragma unroll
    for (int c0 = 0; c0 < NCAND; c0 += 64)
        lds_scs[w][c0 + lane] = srow[c0 + lane];
    if (lane < 8) lds_topc[w][lane] = tsrc[(size_t)t * 8 + lane] & 63;

    unsigned prefix = 0; int k = 128;
    #pragma unroll
    for (int shift = 24; shift >= 0; shift -= 8) {
        lds_hist[w][lane] = 0;
        lds_hist[w][lane + 64] = 0;
        lds_hist[w][lane + 128] = 0;
        lds_hist[w][lane + 192] = 0;
        unsigned mhi = (shift == 24) ? 0u : (0xFFFFFFFFu << (shift + 8));
        #pragma unroll
        for (int ii = 0; ii < NCAND; ii += 64) {
            unsigned key = mapkey(lds_scs[w][ii + lane]);
            if ((key & mhi) == prefix) atomicAdd(&lds_hist[w][(key >> shift) & 255], 1);
        }
        int s0 = lds_hist[w][4 * lane], s1 = lds_hist[w][4 * lane + 1];
        int s2 = lds_hist[w][4 * lane + 2], s3 = lds_hist[w][4 * lane + 3];
        int sl = s0 + s1 + s2 + s3;
        int suf = sl;
        #pragma unroll
        for (int o = 1; o < 64; o <<= 1) {
            int ov = __shfl_down(suf, o);
            if (lane + o < 64) suf += ov;
        }
        int run = suf - sl;
        int seld = -1, selk = 0;
        if (run < k && k <= run + s3) { seld = 4 * lane + 3; selk = k - run; }
        run += s3;
        if (seld < 0 && run < k && k <= run + s2) { seld = 4 * lane + 2; selk = k - run; }
        run += s2;
        if (seld < 0 && run < k && k <= run + s1) { seld = 4 * lane + 1; selk = k - run; }
        run += s1;
        if (seld < 0 && run < k && k <= run + s0) { seld = 4 * lane + 0; selk = k - run; }
        u64 mk = __ballot(seld >= 0);
        int owner = __ffsll(mk) - 1;
        int sd = __shfl(seld, owner);
        k = __shfl(selk, owner);
        prefix |= ((unsigned)sd) << shift;
    }
    unsigned thrkey = prefix;

    float tau = tausrc[(size_t)t * taustride + tauoff];
    int basec = 0;
    float lsum = 0.f, lmaxs = -3.0e38f;
    #pragma unroll
    for (int c0 = 0; c0 < NCAND; c0 += 64) {
        float s = lds_scs[w][c0 + lane];
        lmaxs = fmaxf(lmaxs, s);
        bool pred = (mapkey(s) >= thrkey);
        float eg = 0.f;
        if (pred) {
            float raw = s - tau;
            float g2 = raw > 0.f ? raw : 1e-8f * expf(raw);
            eg = expf(g2) - 1.0f;
            lsum += eg;
        }
        u64 mk = __ballot(pred);
        int pos = basec + __popcll(mk & ((1ull << lane) - 1ull));
        if (pred && pos < CAP) {
            lds_hist[w][pos] = c0 + lane;
            lds_keg[w][pos] = eg;
        }
        basec += __popcll(mk);
    }
    #pragma unroll
    for (int o = 1; o < 64; o <<= 1) {
        lsum += __shfl_xor(lsum, o);
        lmaxs = fmaxf(lmaxs, __shfl_xor(lmaxs, o));
    }
    float rawm = lmaxs - tau;
    float gm = rawm > 0.f ? rawm : 1e-8f * expf(rawm);
    float egm = expf(gm) - 1.0f;
    float scalev = tanhf(egm) / (lsum + 1e-8f);
    int nkept = basec < CAP ? basec : CAP;

    for (int p = lane; p < nkept; p += 64) {
        int i = lds_hist[w][p];
        float eg = lds_keg[w][p];
        int neuron = (lds_topc[w][i >> LGCS] << LGCS) + (i & CSM);
        gidx[(size_t)t * CAP + p] = neuron;
        gval[(size_t)t * CAP + p] = eg * scalev;
    }
    if (lane == 0) gcnt[t] = nkept;

    #pragma unroll
    for (int c0 = 0; c0 < NCAND; c0 += 64) {
        int i = c0 + lane;
        float s = lds_scs[w][i];
        float wv = 0.f;
        if (mapkey(s) >= thrkey) {
            float raw = s - tau;
            float g2 = raw > 0.f ? raw : 1e-8f * expf(raw);
            wv = (expf(g2) - 1.0f) * scalev;
        }
        srow[i] = wv;
    }
}

// ---------------- block-sparse sense+emit (phase A via global_load_lds + XOR swizzle) ----------------
template<int NCL>
__global__ __launch_bounds__(256) void sense_bs_kernel(
    const u16* __restrict__ hbf,
    const u16* __restrict__ ntab,      // [64c][NCL][1024]
    const u16* __restrict__ ntabT,     // [64c][1024][NCL]
    const float* __restrict__ Wg,
    const u32* __restrict__ entries,
    const u32* __restrict__ tiletab,
    const int* __restrict__ ntiles,
    u16* __restrict__ partial)
{
    constexpr int NTP = NCL + 8;
    constexpr int PS  = NCL + 8;       // padded sP row stride
    constexpr int NFR = NCL / 16;
    constexpr int LQ = (NCL == 64) ? 3 : 4;
    // phase A: sH[64][64] + sN[NCL][64], LINEAR rows (global_load_lds dest), XOR-swizzled data
    __shared__ __align__(16) char smem[(64 + NCL) * 128 + 64 * PS * 2 + 256];
    u16* sH = (u16*)smem;
    u16* sN = (u16*)(smem + 64 * 128);
    u16* sNT = (u16*)smem;                    // phase B aliases phase-A region
    u16* sP = (u16*)(smem + (64 + NCL) * 128);
    u32* ent = (u32*)(smem + (64 + NCL) * 128 + 64 * PS * 2);

    int bsw = ((int)blockIdx.x & 7) * 80 + ((int)blockIdx.x >> 3);  // XCD chunk swizzle
    if (bsw >= *ntiles) return;
    u32 te = tiletab[bsw];
    int c = (int)(te >> 16) & 63;
    int e0 = (int)(te & 0x3FFu) * 64;

    int tid = threadIdx.x;
    int w = tid >> 6, lane = tid & 63;
    int l15 = lane & 15, hi4 = lane >> 4;

    if (tid < 64) ent[tid] = entries[e0 + tid];
    __syncthreads();

    const u16* nbase = ntab + (size_t)c * NCL * 1024;
    const u16* ntT = ntabT + (size_t)c * NCL * 1024;

    // staging lane geometry: 1KB per wave-op = 8 rows x 128B; lane covers row blk*8+(lane>>3),
    // physical granule lane&7; source granule XOR-swizzled so reads are conflict-free.
    int srow8 = lane >> 3;                 // 0..7 (also row&7)
    int sgr = (lane & 7) ^ srow8;          // swizzled source granule

    f32x4 acc[NFR];
    #pragma unroll
    for (int nf = 0; nf < NFR; ++nf) { acc[nf][0] = 0.f; acc[nf][1] = 0.f; acc[nf][2] = 0.f; acc[nf][3] = 0.f; }

    for (int k0 = 0; k0 < 1024; k0 += 64) {
        __syncthreads();
        #pragma unroll
        for (int u = 0; u < 2; ++u) {
            int blk = w * 2 + u;
            int row = blk * 8 + srow8;
            int t = (int)(ent[row] & 4095u);
            gload16(&hbf[(size_t)t * 1024 + k0 + sgr * 8], sH + blk * 512);
        }
        #pragma unroll
        for (int u = 0; u < NCL / 32; ++u) {
            int blk = w * (NCL / 32) + u;
            int row = blk * 8 + srow8;
            gload16(&nbase[(size_t)row * 1024 + k0 + sgr * 8], sN + blk * 512);
        }
        __syncthreads();
        #pragma unroll
        for (int kc = 0; kc < 2; ++kc) {
            int ga = (((kc * 4 + hi4) ^ (l15 & 7))) * 8;   // swizzled read granule
            s16x8 af = *(const s16x8*)&sH[(w * 16 + l15) * 64 + ga];
            #pragma unroll
            for (int nf = 0; nf < NFR; ++nf) {
                s16x8 bf = *(const s16x8*)&sN[(nf * 16 + l15) * 64 + ga];
                acc[nf] = MFMA16(af, bf, acc[nf]);
            }
        }
    }
    __syncthreads();

    // W-scale -> P (bf16) in LDS (padded stride PS)
    int row0 = w * 16 + hi4 * 4;
    u32 erow[4]; bool evalid[4];
    #pragma unroll
    for (int jj = 0; jj < 4; ++jj) { erow[jj] = ent[row0 + jj]; evalid[jj] = (erow[jj] != 0xFFFFFFFFu); }
    #pragma unroll
    for (int jj = 0; jj < 4; ++jj) {
        int t = (int)(erow[jj] & 4095u), s = (int)((erow[jj] >> 12) & 7u);
        const float* wrow = Wg + (size_t)t * (8 * NCL) + s * NCL;
        #pragma unroll
        for (int nf = 0; nf < NFR; ++nf) {
            float wv = wrow[nf * 16 + l15];
            sP[(row0 + jj) * PS + nf * 16 + l15] = f2bf(acc[nf][jj] * wv);
        }
    }
    __syncthreads();

    // ---- Phase B: OUT = P @ N (K=NCL); staged from pre-transposed ntabT ----
    for (int dch = 0; dch < 16; ++dch) {
        int d0 = dch * 64;
        __syncthreads();
        #pragma unroll
        for (int u = 0; u < NCL / 32; ++u) {
            int v = tid + u * 256;
            int dr = v >> LQ, jq = v & ((1 << LQ) - 1);
            uint4 t4 = *(const uint4*)&ntT[(size_t)(d0 + dr) * NCL + jq * 8];
            *(uint4*)&sNT[dr * NTP + jq * 8] = t4;
        }
        __syncthreads();
        f32x4 ab[4];
        #pragma unroll
        for (int df = 0; df < 4; ++df) { ab[df][0] = 0.f; ab[df][1] = 0.f; ab[df][2] = 0.f; ab[df][3] = 0.f; }
        #pragma unroll
        for (int kc = 0; kc < NCL / 32; ++kc) {
            s16x8 af = *(const s16x8*)&sP[(w * 16 + l15) * PS + kc * 32 + hi4 * 8];
            #pragma unroll
            for (int df = 0; df < 4; ++df) {
                s16x8 bf = *(const s16x8*)&sNT[(df * 16 + l15) * NTP + kc * 32 + hi4 * 8];
                ab[df] = MFMA16(af, bf, ab[df]);
            }
        }
        #pragma unroll
        for (int jj = 0; jj < 4; ++jj) {
            if (evalid[jj]) {
                int t = (int)(erow[jj] & 4095u), s = (int)((erow[jj] >> 12) & 7u);
                u16* prow = partial + ((size_t)t * 8 + s) * 1024 + d0;
                #pragma unroll
                for (int df = 0; df < 4; ++df)
                    prow[df * 16 + l15] = f2bf(ab[df][jj]);
            }
        }
    }
}

// ---------------- reduce 8 slot-partials per token ----------------
__global__ __launch_bounds__(256) void slot_reduce_kernel(
    const u16* __restrict__ partial, u16* __restrict__ outq, float* __restrict__ outadd)
{
    int t = blockIdx.x, tid = threadIdx.x;
    int d0 = tid * 4;
    float s0 = 0.f, s1 = 0.f, s2 = 0.f, s3 = 0.f;
    #pragma unroll
    for (int s = 0; s < 8; ++s) {
        ushort4 u = *(const ushort4*)&partial[((size_t)t * 8 + s) * 1024 + d0];
        s0 += __uint_as_float((u32)u.x << 16);
        s1 += __uint_as_float((u32)u.y << 16);
        s2 += __uint_as_float((u32)u.z << 16);
        s3 += __uint_as_float((u32)u.w << 16);
    }
    if (outq) {
        int b = t >> 10, st = t & 1023;
        int head = d0 >> 6, dh = d0 & 63;
        ushort4 o;
        o.x = f2bf(s0); o.y = f2bf(s1); o.z = f2bf(s2); o.w = f2bf(s3);
        *(ushort4*)&outq[(((size_t)b * 16 + head) * 1024 + st) * 64 + dh] = o;
    } else {
        float* op = outadd + (size_t)t * 1024 + d0;
        float4 cur = *(const float4*)op;
        cur.x += s0; cur.y += s1; cur.z += s2; cur.w += s3;
        *(float4*)op = cur;
    }
}

// ---------------- nfreq partials + cprob partial sums ----------------
__global__ __launch_bounds__(256) void nfreq_partial_kernel(
    const int* __restrict__ gidx, const float* __restrict__ gval,
    const int* __restrict__ gcnt, const float* __restrict__ cprob,
    float* __restrict__ partials, float* __restrict__ cpart2)
{
    __shared__ float hist[8192];
    __shared__ float csum[4][64];
    int slice = blockIdx.x, gate = blockIdx.y;
    int N = (gate == 3) ? 8192 : 4096;
    int tid = threadIdx.x;
    int w = tid >> 6, lane = tid & 63;
    for (int i = tid; i < N; i += 256) hist[i] = 0.f;

    {
        const float* cp = cprob + (size_t)gate * NTOK * 64;
        float cs = 0.f;
        #pragma unroll
        for (int i = 0; i < 16; ++i) {
            int t = slice * 64 + i * 4 + w;
            cs += cp[(size_t)t * 64 + lane];
        }
        csum[w][lane] = cs;
    }
    __syncthreads();

    const int* gi = gidx + (size_t)gate * NTOK * CAP;
    const float* gv = gval + (size_t)gate * NTOK * CAP;
    const int* gc = gcnt + gate * NTOK;
    #pragma unroll 4
    for (int i = 0; i < 16; ++i) {
        int t = slice * 64 + i * 4 + w;
        int cnt = gc[t];
        for (int p = lane; p < cnt; p += 64) {
            int n = gi[(size_t)t * CAP + p];
            float v = gv[(size_t)t * CAP + p];
            atomicAdd(&hist[n], v);
        }
    }
    __syncthreads();
    float* op = partials + ((size_t)gate * 64 + slice) * 8192;
    for (int i = tid; i < N; i += 256) op[i] = hist[i];
    if (tid < 64)
        cpart2[((size_t)gate * 64 + slice) * 64 + tid] =
            csum[0][tid] + csum[1][tid] + csum[2][tid] + csum[3][tid];
}

// ---------------- aux: parallel reduce (84 blocks) ----------------
__global__ __launch_bounds__(256) void aux2_kernel(const float* __restrict__ partials,
                                                   const float* __restrict__ cpart2,
                                                   float* __restrict__ outp)
{
    __shared__ float red[4];
    __shared__ float cred[4][64];
    int bid = blockIdx.x, tid = threadIdx.x;
    float local = 0.f;
    if (bid < 80) {
        int gn = bid * 256 + tid;
        int gate = (gn < 12288) ? (gn >> 12) : 3;
        int ln = (gn < 12288) ? (gn & 4095) : (gn - 12288);
        const float* base = partials + (size_t)gate * 64 * 8192 + ln;
        float s = 0.f;
        #pragma unroll 8
        for (int c = 0; c < 64; ++c) s += base[(size_t)c * 8192];
        float Nf = (gate == 3) ? 8192.f : 4096.f;
        float f = s * (1.0f / 4096.0f);
        float d = f - 1.0f / Nf;
        local = d * d * Nf;
    } else {
        int gate = bid - 80;
        int w = tid >> 6, lane = tid & 63;
        const float* base = cpart2 + (size_t)gate * 64 * 64;
        float s = 0.f;
        #pragma unroll
        for (int i = 0; i < 16; ++i) s += base[(size_t)(i * 4 + w) * 64 + lane];
        cred[w][lane] = s;
        __syncthreads();
        if (tid < 64) {
            float tot = cred[0][tid] + cred[1][tid] + cred[2][tid] + cred[3][tid];
            float f = tot * (1.0f / 4096.0f);
            float d = f - (1.0f / 64.0f);
            local = d * d * 64.0f;
        }
    }
    #pragma unroll
    for (int o = 1; o < 64; o <<= 1) local += __shfl_xor(local, o);
    if ((tid & 63) == 0) red[tid >> 6] = local;
    __syncthreads();
    if (tid == 0) atomicAdd(outp, red[0] + red[1] + red[2] + red[3]);
}

// ---------------- MFMA flash attention, causal, d=64 — SPLIT-K partials ----------------
__global__ __launch_bounds__(256) void attn_split_kernel(const u16* __restrict__ Qb,
                                                         const u16* __restrict__ Kb,
                                                         const u16* __restrict__ Vb,
                                                         u16* __restrict__ Opart,
                                                         float2* __restrict__ mlb)
{
    __shared__ __align__(16) u32 VT[2048];
    __shared__ float csh[128];
    int qt = blockIdx.x;
    int bh = blockIdx.y;
    int z = blockIdx.z;
    int tid = threadIdx.x;
    int w = tid >> 6, lane = tid & 63;
    int hi = lane >> 5, l31 = lane & 31;
    int qb = qt * 128;
    int qcol = qb + w * 32 + l31;
    int wqmax = qb + w * 32 + 31;
    int kt0 = z * (qt + 1);
    int kt1 = kt0 + (qt + 1);

    const u16* Qbase = Qb + (size_t)bh * 1024 * 64;
    const u16* Kbase = Kb + (size_t)bh * 1024 * 64;
    const u16* Vbase = Vb + (size_t)bh * 1024 * 64;

    s16x8 qf[4];
    #pragma unroll
    for (int c = 0; c < 4; ++c)
        qf[c] = *(const s16x8*)&Qbase[(size_t)qcol * 64 + c * 16 + hi * 8];

    int vkey = 2 * (tid & 31);
    int vd = (tid >> 5) * 8;
    int base0 = kt0 * 64;
    uint4 va  = *(const uint4*)&Vbase[(size_t)(base0 + vkey) * 64 + vd];
    uint4 vb2 = *(const uint4*)&Vbase[(size_t)(base0 + vkey + 1) * 64 + vd];

    s16x8 kf[2][4];
    #pragma unroll
    for (int s = 0; s < 2; ++s)
        #pragma unroll
        for (int c = 0; c < 4; ++c)
            kf[s][c] = *(const s16x8*)&Kbase[(size_t)(base0 + s * 32 + l31) * 64 + c * 16 + hi * 8];

    float m = -3.0e38f, lden = 0.f;
    f32x16 oacc0, oacc1;
    #pragma unroll
    for (int r = 0; r < 16; ++r) { oacc0[r] = 0.f; oacc1[r] = 0.f; }

    for (int kt = kt0; kt < kt1; ++kt) {
        __syncthreads();
        {
            U16x8 ua, ub; ua.u = va; ub.u = vb2;
            #pragma unroll
            for (int j = 0; j < 8; ++j) {
                int d = vd + j;
                u32 pk = (u32)ua.s[j] | ((u32)ub.s[j] << 16);
                VT[(u32)((d * 32 + (tid & 31)) ^ ((d & 7) << 2))] = pk;
            }
        }
        __syncthreads();

        bool active = (kt * 64) <= wqmax;
        f32x16 s0, s1;
        if (active) {
            #pragma unroll
            for (int r = 0; r < 16; ++r) { s0[r] = 0.f; s1[r] = 0.f; }
            #pragma unroll
            for (int c = 0; c < 4; ++c) {
                s0 = MFMA32(kf[0][c], qf[c], s0);
                s1 = MFMA32(kf[1][c], qf[c], s1);
            }
        }
        if (kt + 1 < kt1) {
            int nb = (kt + 1) * 64;
            va  = *(const uint4*)&Vbase[(size_t)(nb + vkey) * 64 + vd];
            vb2 = *(const uint4*)&Vbase[(size_t)(nb + vkey + 1) * 64 + vd];
            if (nb <= wqmax) {
                #pragma unroll
                for (int s = 0; s < 2; ++s)
                    #pragma unroll
                    for (int c = 0; c < 4; ++c)
                        kf[s][c] = *(const s16x8*)&Kbase[(size_t)(nb + s * 32 + l31) * 64 + c * 16 + hi * 8];
            }
        }
        if (active) {
            float p0[16], p1[16];
            float pmax = -3.0e38f;
            #pragma unroll
            for (int r = 0; r < 16; ++r) {
                int crow = (r & 3) + 8 * (r >> 2) + 4 * hi;
                int k0 = kt * 64 + crow;
                float v0 = (k0 <= qcol) ? s0[r] * 0.125f : -3.0e38f;
                float v1 = (k0 + 32 <= qcol) ? s1[r] * 0.125f : -3.0e38f;
                p0[r] = v0; p1[r] = v1;
                pmax = fmaxf(pmax, fmaxf(v0, v1));
            }
            pmax = fmaxf(pmax, __shfl_xor(pmax, 32));
            float mn = fmaxf(m, pmax);
            float corr = __expf(m - mn);
            float rs = 0.f;
            #pragma unroll
            for (int r = 0; r < 16; ++r) {
                p0[r] = __expf(p0[r] - mn);
                p1[r] = __expf(p1[r] - mn);
                rs += p0[r] + p1[r];
            }
            rs += __shfl_xor(rs, 32);
            lden = lden * corr + rs;
            m = mn;
            if (hi == 0) csh[w * 32 + l31] = corr;
            float c16[16];
            #pragma unroll
            for (int r = 0; r < 16; ++r)
                c16[r] = csh[w * 32 + ((r & 3) + 8 * (r >> 2) + 4 * hi)];
            #pragma unroll
            for (int r = 0; r < 16; ++r) { oacc0[r] *= c16[r]; oacc1[r] *= c16[r]; }

            #pragma unroll
            for (int sub = 0; sub < 2; ++sub) {
                u32 e[8], x[8];
                #pragma unroll
                for (int j = 0; j < 8; ++j) {
                    float lo = sub ? p1[2 * j] : p0[2 * j];
                    float hi2 = sub ? p1[2 * j + 1] : p0[2 * j + 1];
                    e[j] = pkbf(lo, hi2);
                }
                #pragma unroll
                for (int j = 0; j < 8; ++j) x[j] = (u32)__shfl_xor((int)e[j], 32);
                Dw4 t0, t1;
                t0.d[0] = hi ? x[2] : e[0];
                t0.d[1] = hi ? x[3] : e[1];
                t0.d[2] = hi ? e[2] : x[0];
                t0.d[3] = hi ? e[3] : x[1];
                t1.d[0] = hi ? x[6] : e[4];
                t1.d[1] = hi ? x[7] : e[5];
                t1.d[2] = hi ? e[6] : x[4];
                t1.d[3] = hi ? e[7] : x[5];
                int kb0 = sub * 32 + hi * 8;
                int kb1 = kb0 + 16;
                int d0 = l31, d1 = 32 + l31;
                const char* vtb = (const char*)VT;
                s16x8 vf;
                vf = *(const s16x8*)(vtb + (((d0 * 128 + kb0 * 2)) ^ ((d0 & 7) << 4)));
                oacc0 = MFMA32(t0.v, vf, oacc0);
                vf = *(const s16x8*)(vtb + (((d1 * 128 + kb0 * 2)) ^ ((d1 & 7) << 4)));
                oacc1 = MFMA32(t0.v, vf, oacc1);
                vf = *(const s16x8*)(vtb + (((d0 * 128 + kb1 * 2)) ^ ((d0 & 7) << 4)));
                oacc0 = MFMA32(t1.v, vf, oacc0);
                vf = *(const s16x8*)(vtb + (((d1 * 128 + kb1 * 2)) ^ ((d1 & 7) << 4)));
                oacc1 = MFMA32(t1.v, vf, oacc1);
            }
        }
    }
    size_t pi = (size_t)(z * 8 + qt) * 64 + bh;
    if (hi == 0)
        mlb[pi * 128 + w * 32 + l31] = make_float2(m, lden);
    #pragma unroll
    for (int r = 0; r < 16; ++r) {
        int crow = (r & 3) + 8 * (r >> 2) + 4 * hi;
        u16* orow = Opart + (pi * 128 + w * 32 + crow) * 64;
        orow[l31]      = f2bf(oacc0[r]);
        orow[32 + l31] = f2bf(oacc1[r]);
    }
}

// ---------------- merge the 2 split partials -> attn_bf ----------------
__global__ __launch_bounds__(256) void attn_merge_kernel(const u16* __restrict__ Opart,
                                                         const float2* __restrict__ mlb,
                                                         u16* __restrict__ outbf)
{
    int t = blockIdx.x, tid = threadIdx.x;
    int b = t >> 10, s = t & 1023;
    int qt = s >> 7, qrow = s & 127;
    int hh = tid >> 4, q4 = (tid & 15) * 4;
    size_t pi0 = (size_t)qt * 64 + (b * 16 + hh);
    size_t pi1 = (size_t)(8 + qt) * 64 + (b * 16 + hh);
    float2 ml0 = mlb[pi0 * 128 + qrow];
    float2 ml1 = mlb[pi1 * 128 + qrow];
    float M = fmaxf(ml0.x, ml1.x);
    float w0 = __expf(ml0.x - M);
    float w1 = __expf(ml1.x - M);
    float inv = 1.0f / (ml0.y * w0 + ml1.y * w1);
    ushort4 a = *(const ushort4*)&Opart[(pi0 * 128 + qrow) * 64 + q4];
    ushort4 c = *(const ushort4*)&Opart[(pi1 * 128 + qrow) * 64 + q4];
    ushort4 o;
    o.x = f2bf((bf2f(a.x) * w0 + bf2f(c.x) * w1) * inv);
    o.y = f2bf((bf2f(a.y) * w0 + bf2f(c.y) * w1) * inv);
    o.z = f2bf((bf2f(a.z) * w0 + bf2f(c.z) * w1) * inv);
    o.w = f2bf((bf2f(a.w) * w0 + bf2f(c.w) * w1) * inv);
    *(ushort4*)&outbf[(size_t)t * 1024 + hh * 64 + q4] = o;
}

extern "C" void kernel_launch(void* const* d_in, const int* in_sizes, int n_in,
                              void* d_out, int out_size, void* d_ws, size_t ws_size,
                              hipStream_t stream) {
    const float* x            = (const float*)d_in[0];
    const float* neuron_emb   = (const float*)d_in[1];
    const float* proj_attn_k  = (const float*)d_in[2];
    const float* proj_attn_b  = (const float*)d_in[3];
    const float* tau_attn_k   = (const float*)d_in[4];
    const float* tau_attn_b   = (const float*)d_in[5];
    const float* proj_know_k  = (const float*)d_in[6];
    const float* proj_know_b  = (const float*)d_in[7];
    const float* tau_know_k   = (const float*)d_in[8];
    const float* tau_know_b   = (const float*)d_in[9];
    const float* cluster_qk   = (const float*)d_in[10];
    const float* cluster_v    = (const float*)d_in[11];
    const float* cluster_know = (const float*)d_in[12];
    const float* qk_neurons   = (const float*)d_in[13];
    const float* v_neurons    = (const float*)d_in[14];
    const float* know_neurons = (const float*)d_in[15];
    const float* expand_O     = (const float*)d_in[16];
    const float* ln1_s        = (const float*)d_in[17];
    const float* ln1_b        = (const float*)d_in[18];
    const float* ln2_s        = (const float*)d_in[19];
    const float* ln2_b        = (const float*)d_in[20];
    float* out = (float*)d_out;

    char* wsb = (char*)d_ws;
    size_t off = 0;
    auto alloc = [&](size_t bytes) -> void* {
        void* p = wsb + off;
        off = (off + bytes + 255) & ~(size_t)255;
        return p;
    };
    u16*   emb16    = (u16*)alloc((size_t)16384 * 128 * 2);
    float* ce_norm  = (float*)alloc((size_t)3 * 64 * 128 * 4);
    u16*   nbf      = (u16*)alloc((size_t)16384 * 1024 * 2);
    float* h1       = (float*)alloc((size_t)NTOK * 1024 * 4);
    u16*   h1bf     = (u16*)alloc((size_t)NTOK * 1024 * 2);
    float* h_all    = (float*)alloc((size_t)NTOK * 384 * 4);
    float* tau_all  = (float*)alloc((size_t)NTOK * 3 * 4);
    u16*   hgbf     = (u16*)alloc((size_t)4 * NTOK * 128 * 2);
    int*   gidx     = (int*)alloc((size_t)4 * NTOK * CAP * 4);
    float* gvalp    = (float*)alloc((size_t)4 * NTOK * CAP * 4);
    int*   gcnt     = (int*)alloc((size_t)4 * NTOK * 4);
    int*   topcg    = (int*)alloc((size_t)4 * NTOK * 8 * 4);
    float* Wattn    = (float*)alloc((size_t)3 * NTOK * 512 * 4);
    u32*   entries  = (u32*)alloc((size_t)4 * 40960 * 4);
    u32*   tiletab  = (u32*)alloc((size_t)4 * 640 * 4);
    int*   ntiles   = (int*)alloc((size_t)4 * 4);
    u16*   qkv      = (u16*)alloc((size_t)3 * NTOK * 1024 * 2);
    u16*   projA_t  = (u16*)alloc((size_t)384 * 1024 * 2);
    u16*   know_t   = (u16*)alloc((size_t)128 * 1024 * 2);
    u16*   exp_t    = (u16*)alloc((size_t)1024 * 1024 * 2);
    float* cprob    = (float*)alloc((size_t)4 * NTOK * 64 * 4);
    float* cpart2   = (float*)alloc((size_t)4 * 64 * 64 * 4);
    u16*   spartial = (u16*)alloc((size_t)NTOK * 8 * 1024 * 2);
    u16*   Opart    = (u16*)alloc((size_t)2 * 8 * 64 * 128 * 64 * 2);
    float2* mlb     = (float2*)alloc((size_t)2 * 8 * 64 * 128 * 8);

    float* h_know   = h_all;
    float* tau_kn   = tau_all;
    float* Wknow    = Wattn;
    float* partials = Wattn + (size_t)NTOK * 1024;
    u16* ntT_qk   = (u16*)h1;
    u16* ntT_v    = (u16*)h1 + (size_t)4096 * 1024;
    u16* ntT_know = (u16*)h1;

    u16* Qbuf = qkv;
    u16* Kbuf = qkv + (size_t)NTOK * 1024;
    u16* Vbuf = qkv + (size_t)2 * NTOK * 1024;
    u16* attn_bf = h1bf;

    hipMemsetAsync(out + (size_t)NTOK * 1024, 0, 4, stream);

    norm_rows_kernel<<<16384 / 4, 256, 0, stream>>>(neuron_emb, emb16, nullptr, 16384);
    norm_rows_kernel<<<16, 256, 0, stream>>>(cluster_qk, nullptr, ce_norm, 64);
    norm_rows_kernel<<<16, 256, 0, stream>>>(cluster_v, nullptr, ce_norm + 64 * 128, 64);
    norm_rows_kernel<<<16, 256, 0, stream>>>(cluster_know, nullptr, ce_norm + 2 * 64 * 128, 64);
    cast_bf16_kernel<<<4096, 256, 0, stream>>>(qk_neurons, nbf, 4096 * 1024);
    cast_bf16_kernel<<<4096, 256, 0, stream>>>(v_neurons, nbf + (size_t)4096 * 1024, 4096 * 1024);
    cast_bf16_kernel<<<8192, 256, 0, stream>>>(know_neurons, nbf + (size_t)8192 * 1024, 8192 * 1024);
    transpose_cast_kernel<<<dim3(6, 16), dim3(64, 4), 0, stream>>>(proj_attn_k, projA_t, 384, 1024);
    transpose_cast_kernel<<<dim3(2, 16), dim3(64, 4), 0, stream>>>(proj_know_k, know_t, 128, 1024);
    transpose_cast_kernel<<<dim3(16, 16), dim3(64, 4), 0, stream>>>(expand_O, exp_t, 1024, 1024);

    ln_kernel<<<NTOK, 256, 0, stream>>>(x, ln1_s, ln1_b, h1, h1bf);
    gemm_mfma_kernel<<<dim3(3, 32), 256, 0, stream>>>(h1bf, projA_t, proj_attn_b, nullptr, h_all, 384, 1024);
    vecproj_kernel<<<NTOK, 64, 0, stream>>>(h1, tau_attn_k, tau_attn_b, tau_all, 3);
    ntab_transpose_kernel<<<dim3(64, 16, 1), dim3(64, 4), 0, stream>>>(nbf, ntT_qk, 64);
    ntab_transpose_kernel<<<dim3(64, 16, 1), dim3(64, 4), 0, stream>>>(
        nbf + (size_t)4096 * 1024, ntT_v, 64);

    cluster_kernel<<<dim3(NTOK / 32, 3), 256, 0, stream>>>(h_all, 384, ce_norm, cprob, topcg, 0);
    listbuild_kernel<<<3, 1024, 0, stream>>>(topcg, entries, tiletab, ntiles);
    cast_gateh_kernel<<<NTOK, 256, 0, stream>>>(h_all, 384, 3, hgbf);
    score_bs_kernel<64><<<dim3(640, 3), 256, 0, stream>>>(hgbf, emb16, Wattn, entries, tiletab, ntiles);
    gate_select_kernel<512, 6><<<dim3(1024, 3), 256, 0, stream>>>(
        Wattn, tau_all, 3, topcg, gidx, gvalp, gcnt, 0);

    for (int g = 0; g < 3; ++g) {
        const u16* tab  = nbf + (g == 2 ? (size_t)4096 * 1024 : 0);
        const u16* tabT = (g == 2) ? ntT_v : ntT_qk;
        sense_bs_kernel<64><<<640, 256, 0, stream>>>(
            h1bf, tab, tabT, Wattn + (size_t)g * NTOK * 512,
            entries + (size_t)g * 40960, tiletab + (size_t)g * 640, ntiles + g, spartial);
        u16* outq = (g == 0) ? Qbuf : (g == 1) ? Kbuf : Vbuf;
        slot_reduce_kernel<<<NTOK, 256, 0, stream>>>(spartial, outq, nullptr);
    }

    attn_split_kernel<<<dim3(8, 64, 2), 256, 0, stream>>>(Qbuf, Kbuf, Vbuf, Opart, mlb);
    attn_merge_kernel<<<NTOK, 256, 0, stream>>>(Opart, mlb, attn_bf);
    gemm_mfma_kernel<<<dim3(8, 32), 256, 0, stream>>>(attn_bf, exp_t, nullptr, x, out, 1024, 1024);

    ln_kernel<<<NTOK, 256, 0, stream>>>(out, ln2_s, ln2_b, h1, h1bf);
    gemm_mfma_kernel<<<dim3(1, 32), 256, 0, stream>>>(h1bf, know_t, proj_know_b, nullptr, h_know, 128, 1024);
    vecproj_kernel<<<NTOK, 64, 0, stream>>>(h1, tau_know_k, tau_know_b, tau_kn, 1);
    ntab_transpose_kernel<<<dim3(64, 16, 2), dim3(64, 4), 0, stream>>>(
        nbf + (size_t)8192 * 1024, ntT_know, 128);

    cluster_kernel<<<dim3(NTOK / 32, 1), 256, 0, stream>>>(h_know, 128, ce_norm + 2 * 64 * 128,
                                                           cprob, topcg, 3);
    listbuild_kernel<<<1, 1024, 0, stream>>>(topcg + (size_t)3 * NTOK * 8,
                                             entries + (size_t)3 * 40960,
                                             tiletab + (size_t)3 * 640, ntiles + 3);
    cast_gateh_kernel<<<NTOK, 256, 0, stream>>>(h_know, 128, 1, hgbf + (size_t)3 * NTOK * 128);
    score_bs_kernel<128><<<dim3(640, 1), 256, 0, stream>>>(
        hgbf + (size_t)3 * NTOK * 128, emb16 + (size_t)8192 * 128, Wknow,
        entries + (size_t)3 * 40960, tiletab + (size_t)3 * 640, ntiles + 3);
    gate_select_kernel<1024, 7><<<dim3(1024, 1), 256, 0, stream>>>(
        Wknow, tau_kn, 1, topcg, gidx, gvalp, gcnt, 3);
    sense_bs_kernel<128><<<640, 256, 0, stream>>>(
        h1bf, nbf + (size_t)8192 * 1024, ntT_know, Wknow,
        entries + (size_t)3 * 40960, tiletab + (size_t)3 * 640, ntiles + 3, spartial);
    slot_reduce_kernel<<<NTOK, 256, 0, stream>>>(spartial, nullptr, out);

    nfreq_partial_kernel<<<dim3(64, 4), 256, 0, stream>>>(gidx, gvalp, gcnt, cprob, partials, cpart2);
    aux2_kernel<<<84, 256, 0, stream>>>(partials, cpart2, out + (size_t)NTOK * 1024);
}